// Round 2
// baseline (1858.747 us; speedup 1.0000x reference)
//
#include <hip/hip_runtime.h>
#include <hip/hip_bf16.h>

#define LSEQ 4096
#define BSZ 2
#define DMODEL 512
#define DINNER 1024
#define DSTATE 64
#define NHEADS 16
#define CONVDIM 1152
#define DPROJ 2192
#define NPAD 2304
#define NTOK (BSZ*LSEQ)

typedef __attribute__((ext_vector_type(8))) short short8;
typedef __attribute__((ext_vector_type(4))) float f32x4;

__device__ inline unsigned short f2b(float v){
  unsigned int u = __builtin_bit_cast(unsigned int, v);
  unsigned int r = (u + 0x7FFFu + ((u >> 16) & 1u)) >> 16;
  return (unsigned short)r;
}
__device__ inline float b2f(unsigned short u){
  unsigned int x = ((unsigned int)u) << 16;
  return __builtin_bit_cast(float, x);
}

// ---------------- weight transpose + f32->bf16 (src [K][Nsrc] -> dst [Npad][K]) ----
__global__ __launch_bounds__(256) void wconv_t(const float* __restrict__ src,
    unsigned short* __restrict__ dst, int K, int Nsrc, int Npad){
  __shared__ float t[32][33];
  int n0 = blockIdx.x*32, k0 = blockIdx.y*32;
  int tx = threadIdx.x & 31, ty = threadIdx.x >> 5;
  for (int i=0;i<4;i++){
    int k = k0 + ty + i*8; int n = n0 + tx;
    t[ty + i*8][tx] = (n < Nsrc) ? src[(size_t)k*Nsrc + n] : 0.f;
  }
  __syncthreads();
  for (int i=0;i<4;i++){
    int n = n0 + ty + i*8; int k = k0 + tx;
    if (n < Npad) dst[(size_t)n*K + k] = f2b(t[tx][ty + i*8]);
  }
}

// ---------------- layernorm over 512 cols (f32 in) -> bf16 ----------------
__global__ __launch_bounds__(256) void layernorm_k(const float* __restrict__ in,
    const float* __restrict__ w, const float* __restrict__ bb, unsigned short* __restrict__ out){
  int row = blockIdx.x; int tid = threadIdx.x;
  const float* r = in + (size_t)row*DMODEL;
  float v0 = r[tid], v1 = r[tid+256];
  float s = v0+v1, sq = v0*v0+v1*v1;
  for (int m=32;m>=1;m>>=1){ s += __shfl_xor(s,m); sq += __shfl_xor(sq,m); }
  __shared__ float ws_[4], wq_[4];
  int wave = tid>>6, lane = tid&63;
  if (lane==0){ ws_[wave]=s; wq_[wave]=sq; }
  __syncthreads();
  s = ws_[0]+ws_[1]+ws_[2]+ws_[3]; sq = wq_[0]+wq_[1]+wq_[2]+wq_[3];
  float mu = s * (1.f/DMODEL);
  float var = sq * (1.f/DMODEL) - mu*mu;
  float rs = rsqrtf(var + 1e-5f);
  out[(size_t)row*DMODEL + tid]     = f2b((v0-mu)*rs*w[tid] + bb[tid]);
  out[(size_t)row*DMODEL + tid+256] = f2b((v1-mu)*rs*w[tid+256] + bb[tid+256]);
}

// ---------------- bf16 MFMA GEMM: C[M,N] = A[M,K] @ Bt[N,K]^T ----------------
// epi 0: f32 plain ; 1: bf16 gelu(v+bias) ; 2: f32 v+bias+resid ; 3: bf16 plain
__global__ __launch_bounds__(256) void gemm_k(const unsigned short* __restrict__ A,
    const unsigned short* __restrict__ Bt, void* __restrict__ outp,
    int M, int N, int K, int epi, const float* __restrict__ bias, const float* __restrict__ resid){
  __shared__ __align__(16) unsigned short As[128*40];
  __shared__ __align__(16) unsigned short Bs[128*40];
  int tid = threadIdx.x;
  int lane = tid & 63, wave = tid >> 6;
  int wr = wave >> 1, wc = wave & 1;
  int l15 = lane & 15, q = lane >> 4;
  int bm = blockIdx.y, bn = blockIdx.x;
  f32x4 acc[4][4];
  for (int i=0;i<4;i++) for(int j=0;j<4;j++) acc[i][j] = (f32x4){0.f,0.f,0.f,0.f};
  const size_t abase = (size_t)bm*128*K;
  const size_t bbase = (size_t)bn*128*K;
  for (int k0 = 0; k0 < K; k0 += 32){
    for (int i=0;i<2;i++){
      int idx = tid + i*256; int rr = idx>>2, cg = idx&3;
      *(uint4*)(&As[rr*40 + cg*8]) = *(const uint4*)(A + abase + (size_t)rr*K + k0 + cg*8);
      *(uint4*)(&Bs[rr*40 + cg*8]) = *(const uint4*)(Bt + bbase + (size_t)rr*K + k0 + cg*8);
    }
    __syncthreads();
    short8 af[4], bfr[4];
    for (int mt=0;mt<4;mt++) af[mt]  = *(const short8*)(&As[(wr*64+mt*16+l15)*40 + q*8]);
    for (int nt=0;nt<4;nt++) bfr[nt] = *(const short8*)(&Bs[(wc*64+nt*16+l15)*40 + q*8]);
    for (int mt=0;mt<4;mt++)
      for (int nt=0;nt<4;nt++)
        acc[mt][nt] = __builtin_amdgcn_mfma_f32_16x16x32_bf16(af[mt], bfr[nt], acc[mt][nt], 0,0,0);
    __syncthreads();
  }
  int rbase = q*4;
  for (int mt=0;mt<4;mt++) for (int nt=0;nt<4;nt++){
    for (int rr=0;rr<4;rr++){
      int gr = bm*128 + wr*64 + mt*16 + rbase + rr;
      int gc = bn*128 + wc*64 + nt*16 + l15;
      float v = acc[mt][nt][rr];
      if (epi == 0){
        ((float*)outp)[(size_t)gr*N + gc] = v;
      } else if (epi == 1){
        v += bias[gc];
        v = 0.5f*v*(1.f+erff(v*0.70710678118654752f));
        ((unsigned short*)outp)[(size_t)gr*N + gc] = f2b(v);
      } else if (epi == 2){
        v += bias[gc] + resid[(size_t)gr*N + gc];
        ((float*)outp)[(size_t)gr*N + gc] = v;
      } else {
        ((unsigned short*)outp)[(size_t)gr*N + gc] = f2b(v);
      }
    }
  }
}

// ---------------- conv + silu + dt/dA/dtx/B/C prep (per direction; zx is bf16) ----
__global__ __launch_bounds__(256) void prep_k(const unsigned short* __restrict__ zx,
    const float* __restrict__ conv_w, const float* __restrict__ conv_b,
    const float* __restrict__ dt_bias, const float* __restrict__ A_log,
    float* __restrict__ dAb, unsigned short* __restrict__ dtxb, unsigned short* __restrict__ xhb,
    unsigned short* __restrict__ Bb, unsigned short* __restrict__ Cb){
  int inst = blockIdx.x;
  int d = inst >> 13; int rem = inst & 8191;
  int b = rem >> 12; int s = rem & 4095;
  int tid = threadIdx.x;
  int t = d ? (LSEQ-1-s) : s;
  __shared__ float sdt[NHEADS];
  if (tid < NHEADS){
    float raw = b2f(zx[((size_t)b*LSEQ + t)*NPAD + (DINNER+CONVDIM) + tid]) + dt_bias[tid];
    float dt = (raw > 20.f) ? raw : log1pf(expf(raw));
    sdt[tid] = dt;
    dAb[((size_t)(d*BSZ+b)*LSEQ + s)*NHEADS + tid] = expf(-expf(A_log[tid]) * dt);
  }
  __syncthreads();
  size_t tok = (size_t)(d*BSZ+b)*LSEQ + s;
  for (int c = tid; c < CONVDIM; c += 256){
    float acc = conv_b[c];
    #pragma unroll
    for (int k=0;k<4;k++){
      int sig = s - 3 + k;
      if (sig >= 0){
        int tp = d ? (LSEQ-1-sig) : sig;
        acc += conv_w[k*CONVDIM + c] * b2f(zx[((size_t)b*LSEQ + tp)*NPAD + DINNER + c]);
      }
    }
    float v = acc / (1.f + expf(-acc));   // silu
    if (c < DINNER){
      xhb[tok*DINNER + c] = f2b(v);
      dtxb[tok*DINNER + c] = f2b(v * sdt[c >> 6]);
    } else if (c < DINNER + DSTATE){
      Bb[tok*DSTATE + (c - DINNER)] = f2b(v);
    } else {
      Cb[tok*DSTATE + (c - DINNER - DSTATE)] = f2b(v);
    }
  }
}

// ---------------- sequential selective scan ----------------
// grid 256 = (d,b,h,pg); block 256 = p_local(16) x n-quad(16); 4 state elems/thread
__global__ __launch_bounds__(256) void scan_k(const float* __restrict__ dAb,
    const unsigned short* __restrict__ dtxb, const unsigned short* __restrict__ xhb,
    const unsigned short* __restrict__ Bb, const unsigned short* __restrict__ Cb,
    const float* __restrict__ Dh, unsigned short* __restrict__ y0, unsigned short* __restrict__ y1){
  int bx = blockIdx.x;
  int pg = bx & 3, h = (bx>>2)&15, b = (bx>>6)&1, d = bx>>7;
  int tid = threadIdx.x;
  int p_l = tid >> 4, ng = tid & 15, n0 = ng*4;
  unsigned short* yb = d ? y1 : y0;
  size_t tokb = (size_t)(d*BSZ + b)*LSEQ;
  size_t ytokb = (size_t)b*LSEQ;
  __shared__ float sdA[64];
  __shared__ float sdtx[64*16];
  __shared__ float sxh[64*16];
  __shared__ __align__(16) float sB[64*64];
  __shared__ __align__(16) float sC[64*64];
  __shared__ float sy[64*16];
  float hn[4] = {0.f,0.f,0.f,0.f};
  float Dv = Dh[h];
  int pcol = h*64 + pg*16;
  for (int s0=0; s0<LSEQ; s0+=64){
    if (tid < 64) sdA[tid] = dAb[(tokb + s0 + tid)*NHEADS + h];
    for (int i=0;i<4;i++){
      int idx = tid + i*256; int rr = idx>>4, cc = idx&15;
      sdtx[idx] = b2f(dtxb[(tokb+s0+rr)*DINNER + pcol + cc]);
      sxh[idx]  = b2f(xhb [(tokb+s0+rr)*DINNER + pcol + cc]);
    }
    for (int i=0;i<16;i++){
      int idx = tid + i*256; int rr = idx>>6, cc = idx&63;
      sB[idx] = b2f(Bb[(tokb+s0+rr)*DSTATE + cc]);
      sC[idx] = b2f(Cb[(tokb+s0+rr)*DSTATE + cc]);
    }
    __syncthreads();
    for (int j=0;j<64;j++){
      float dA = sdA[j];
      float dtxv = sdtx[j*16 + p_l];
      const float4 Bv = *(const float4*)(&sB[j*64 + n0]);
      const float4 Cv = *(const float4*)(&sC[j*64 + n0]);
      hn[0] = hn[0]*dA + dtxv*Bv.x;
      hn[1] = hn[1]*dA + dtxv*Bv.y;
      hn[2] = hn[2]*dA + dtxv*Bv.z;
      hn[3] = hn[3]*dA + dtxv*Bv.w;
      float yp = hn[0]*Cv.x + hn[1]*Cv.y + hn[2]*Cv.z + hn[3]*Cv.w;
      yp += __shfl_xor(yp, 8);
      yp += __shfl_xor(yp, 4);
      yp += __shfl_xor(yp, 2);
      yp += __shfl_xor(yp, 1);
      if (ng == 0) sy[j*16 + p_l] = yp + Dv * sxh[j*16 + p_l];
    }
    __syncthreads();
    for (int i=0;i<4;i++){
      int idx = tid + i*256; int rr = idx>>4, cc = idx&15;
      int sI = s0 + rr; int tph = d ? (LSEQ-1-sI) : sI;
      yb[(ytokb + tph)*DINNER + pcol + cc] = f2b(sy[idx]);
    }
  }
}

// ---------------- gate: g=y*silu(z), per-dir rmsnorm, sum, ->bf16 ----------------
__global__ __launch_bounds__(256) void gate_k(const unsigned short* __restrict__ y0,
    const unsigned short* __restrict__ y1, const unsigned short* __restrict__ zx,
    const float* __restrict__ mnw, unsigned short* __restrict__ gsum){
  int tok = blockIdx.x; int tid = threadIdx.x;
  __shared__ float g0s[DINNER], g1s[DINNER];
  float ss0 = 0.f, ss1 = 0.f;
  for (int i=0;i<4;i++){
    int c = tid + i*256;
    float z = b2f(zx[(size_t)tok*NPAD + c]);
    float sz = z / (1.f + expf(-z));
    float g0 = b2f(y0[(size_t)tok*DINNER + c]) * sz;
    float g1 = b2f(y1[(size_t)tok*DINNER + c]) * sz;
    g0s[c] = g0; g1s[c] = g1;
    ss0 += g0*g0; ss1 += g1*g1;
  }
  for (int m=32;m>=1;m>>=1){ ss0 += __shfl_xor(ss0,m); ss1 += __shfl_xor(ss1,m); }
  __shared__ float w0[4], w1[4];
  int wave = tid>>6, lane = tid&63;
  if (lane==0){ w0[wave]=ss0; w1[wave]=ss1; }
  __syncthreads();
  ss0 = w0[0]+w0[1]+w0[2]+w0[3];
  ss1 = w1[0]+w1[1]+w1[2]+w1[3];
  float r0 = rsqrtf(ss0*(1.f/DINNER) + 1e-5f);
  float r1 = rsqrtf(ss1*(1.f/DINNER) + 1e-5f);
  for (int i=0;i<4;i++){
    int c = tid + i*256;
    gsum[(size_t)tok*DINNER + c] = f2b((g0s[c]*r0 + g1s[c]*r1) * mnw[c]);
  }
}

extern "C" void kernel_launch(void* const* d_in, const int* in_sizes, int n_in,
                              void* d_out, int out_size, void* d_ws, size_t ws_size,
                              hipStream_t stream){
  const float* x       = (const float*)d_in[0];
  const float* nin_w   = (const float*)d_in[1];
  const float* nin_b   = (const float*)d_in[2];
  const float* nout_w  = (const float*)d_in[3];
  const float* nout_b  = (const float*)d_in[4];
  const float* in_w    = (const float*)d_in[5];
  const float* conv_w  = (const float*)d_in[6];
  const float* conv_b  = (const float*)d_in[7];
  const float* dt_bias = (const float*)d_in[8];
  const float* A_log   = (const float*)d_in[9];
  const float* D_h     = (const float*)d_in[10];
  const float* mnorm_w = (const float*)d_in[11];
  const float* out_w   = (const float*)d_in[12];
  const float* ff_w1   = (const float*)d_in[13];
  const float* ff_b1   = (const float*)d_in[14];
  const float* ff_w2   = (const float*)d_in[15];
  const float* ff_b2   = (const float*)d_in[16];
  float* out = (float*)d_out;

  char* ws = (char*)d_ws;
  size_t off = 0;
  auto alloc = [&](size_t bytes)->char*{
    char* p = ws + off; off = (off + bytes + 255) & ~(size_t)255; return p; };
  unsigned short* xn_bf = (unsigned short*)alloc((size_t)NTOK*DMODEL*2);
  unsigned short* in_wT = (unsigned short*)alloc((size_t)NPAD*DMODEL*2);
  unsigned short* out_wT= (unsigned short*)alloc((size_t)DMODEL*DINNER*2);
  unsigned short* w1T   = (unsigned short*)alloc((size_t)2048*DMODEL*2);
  unsigned short* w2T   = (unsigned short*)alloc((size_t)DMODEL*2048*2);
  unsigned short* zx    = (unsigned short*)alloc((size_t)NTOK*NPAD*2);
  float*          dAb   = (float*)alloc((size_t)2*NTOK*NHEADS*4);
  unsigned short* Bb    = (unsigned short*)alloc((size_t)2*NTOK*DSTATE*2);
  unsigned short* Cb    = (unsigned short*)alloc((size_t)2*NTOK*DSTATE*2);
  unsigned short* dtxb  = (unsigned short*)alloc((size_t)2*NTOK*DINNER*2);
  unsigned short* xhb   = (unsigned short*)alloc((size_t)2*NTOK*DINNER*2);
  unsigned short* y0    = (unsigned short*)alloc((size_t)NTOK*DINNER*2);
  unsigned short* y1    = (unsigned short*)alloc((size_t)NTOK*DINNER*2);
  size_t need = off;
  if (need > ws_size) return;  // diagnostic: fail absmax cleanly instead of faulting

  // aliases into dead regions:
  unsigned short* gsum = dtxb;                                   // 16.8 MB (dtxb dead after scan)
  float* mpre = (float*)(dtxb + (size_t)NTOK*DINNER);            // 16.8 MB (2nd half of dtxb)
  unsigned short* m_bf = xhb;                                    // 8.4 MB  (xhb dead after scan)
  unsigned short* h1   = zx;                                     // 33.6 MB (zx dead after gate_k)

  // weight transposes -> bf16 [N][K]
  wconv_t<<<dim3(NPAD/32,   DMODEL/32), 256, 0, stream>>>(in_w,  in_wT,  DMODEL, DPROJ,  NPAD);
  wconv_t<<<dim3(DMODEL/32, DINNER/32), 256, 0, stream>>>(out_w, out_wT, DINNER, DMODEL, DMODEL);
  wconv_t<<<dim3(2048/32,   DMODEL/32), 256, 0, stream>>>(ff_w1, w1T,    DMODEL, 2048,   2048);
  wconv_t<<<dim3(DMODEL/32, 2048/32),   256, 0, stream>>>(ff_w2, w2T,    2048,   DMODEL, DMODEL);
  // LN in -> bf16
  layernorm_k<<<NTOK, 256, 0, stream>>>(x, nin_w, nin_b, xn_bf);
  // in_proj (shared between directions) -> bf16 zx
  gemm_k<<<dim3(NPAD/128, NTOK/128), 256, 0, stream>>>(xn_bf, in_wT, zx, NTOK, NPAD, DMODEL, 3, nullptr, nullptr);
  // conv/silu/dt prep for both directions
  prep_k<<<2*NTOK, 256, 0, stream>>>(zx, conv_w, conv_b, dt_bias, A_log, dAb, dtxb, xhb, Bb, Cb);
  // selective scan, both directions (bwd writes at flipped/physical position)
  scan_k<<<256, 256, 0, stream>>>(dAb, dtxb, xhb, Bb, Cb, D_h, y0, y1);
  // gate + per-dir rmsnorm + sum (linearity: single out_proj GEMM)
  gate_k<<<NTOK, 256, 0, stream>>>(y0, y1, zx, mnorm_w, gsum);
  // out_proj -> f32 mpre
  gemm_k<<<dim3(DMODEL/128, NTOK/128), 256, 0, stream>>>(gsum, out_wT, mpre, NTOK, DMODEL, DINNER, 0, nullptr, nullptr);
  // LN out -> bf16
  layernorm_k<<<NTOK, 256, 0, stream>>>(mpre, nout_w, nout_b, m_bf);
  // ff1 + gelu -> bf16
  gemm_k<<<dim3(2048/128, NTOK/128), 256, 0, stream>>>(m_bf, w1T, h1, NTOK, 2048, DMODEL, 1, ff_b1, nullptr);
  // ff2 + bias + residual -> f32 out
  gemm_k<<<dim3(DMODEL/128, NTOK/128), 256, 0, stream>>>(h1, w2T, out, NTOK, DMODEL, 2048, 2, ff_b2, x);
}

// Round 3
// 1181.523 us; speedup vs baseline: 1.5732x; 1.5732x over previous
//
#include <hip/hip_runtime.h>
#include <hip/hip_bf16.h>

#define LSEQ 4096
#define BSZ 2
#define DMODEL 512
#define DINNER 1024
#define DSTATE 64
#define NHEADS 16
#define CONVDIM 1152
#define DPROJ 2192
#define NPAD 2304
#define NTOK (BSZ*LSEQ)
#define LC 128
#define NCH (LSEQ/LC)

typedef __attribute__((ext_vector_type(8))) short short8;
typedef __attribute__((ext_vector_type(4))) float f32x4;

__device__ inline unsigned short f2b(float v){
  unsigned int u = __builtin_bit_cast(unsigned int, v);
  unsigned int r = (u + 0x7FFFu + ((u >> 16) & 1u)) >> 16;
  return (unsigned short)r;
}
__device__ inline float b2f(unsigned short u){
  unsigned int x = ((unsigned int)u) << 16;
  return __builtin_bit_cast(float, x);
}

// ---------------- weight transpose + f32->bf16 (src [K][Nsrc] -> dst [Npad][K]) ----
__global__ __launch_bounds__(256) void wconv_t(const float* __restrict__ src,
    unsigned short* __restrict__ dst, int K, int Nsrc, int Npad){
  __shared__ float t[32][33];
  int n0 = blockIdx.x*32, k0 = blockIdx.y*32;
  int tx = threadIdx.x & 31, ty = threadIdx.x >> 5;
  for (int i=0;i<4;i++){
    int k = k0 + ty + i*8; int n = n0 + tx;
    t[ty + i*8][tx] = (n < Nsrc) ? src[(size_t)k*Nsrc + n] : 0.f;
  }
  __syncthreads();
  for (int i=0;i<4;i++){
    int n = n0 + ty + i*8; int k = k0 + tx;
    if (n < Npad) dst[(size_t)n*K + k] = f2b(t[tx][ty + i*8]);
  }
}

// ---------------- layernorm over 512 cols (f32 in) -> bf16 ----------------
__global__ __launch_bounds__(256) void layernorm_k(const float* __restrict__ in,
    const float* __restrict__ w, const float* __restrict__ bb, unsigned short* __restrict__ out){
  int row = blockIdx.x; int tid = threadIdx.x;
  const float* r = in + (size_t)row*DMODEL;
  float v0 = r[tid], v1 = r[tid+256];
  float s = v0+v1, sq = v0*v0+v1*v1;
  for (int m=32;m>=1;m>>=1){ s += __shfl_xor(s,m); sq += __shfl_xor(sq,m); }
  __shared__ float ws_[4], wq_[4];
  int wave = tid>>6, lane = tid&63;
  if (lane==0){ ws_[wave]=s; wq_[wave]=sq; }
  __syncthreads();
  s = ws_[0]+ws_[1]+ws_[2]+ws_[3]; sq = wq_[0]+wq_[1]+wq_[2]+wq_[3];
  float mu = s * (1.f/DMODEL);
  float var = sq * (1.f/DMODEL) - mu*mu;
  float rs = rsqrtf(var + 1e-5f);
  out[(size_t)row*DMODEL + tid]     = f2b((v0-mu)*rs*w[tid] + bb[tid]);
  out[(size_t)row*DMODEL + tid+256] = f2b((v1-mu)*rs*w[tid+256] + bb[tid+256]);
}

// ---------------- bf16 MFMA GEMM: C[M,N] = A[M,K] @ Bt[N,K]^T ----------------
// epi 0: f32 plain ; 1: bf16 gelu(v+bias) ; 2: f32 v+bias+resid ; 3: bf16 plain
__global__ __launch_bounds__(256) void gemm_k(const unsigned short* __restrict__ A,
    const unsigned short* __restrict__ Bt, void* __restrict__ outp,
    int M, int N, int K, int epi, const float* __restrict__ bias, const float* __restrict__ resid){
  __shared__ __align__(16) unsigned short As[128*40];
  __shared__ __align__(16) unsigned short Bs[128*40];
  int tid = threadIdx.x;
  int lane = tid & 63, wave = tid >> 6;
  int wr = wave >> 1, wc = wave & 1;
  int l15 = lane & 15, q = lane >> 4;
  int bm = blockIdx.y, bn = blockIdx.x;
  f32x4 acc[4][4];
  for (int i=0;i<4;i++) for(int j=0;j<4;j++) acc[i][j] = (f32x4){0.f,0.f,0.f,0.f};
  const size_t abase = (size_t)bm*128*K;
  const size_t bbase = (size_t)bn*128*K;
  for (int k0 = 0; k0 < K; k0 += 32){
    for (int i=0;i<2;i++){
      int idx = tid + i*256; int rr = idx>>2, cg = idx&3;
      *(uint4*)(&As[rr*40 + cg*8]) = *(const uint4*)(A + abase + (size_t)rr*K + k0 + cg*8);
      *(uint4*)(&Bs[rr*40 + cg*8]) = *(const uint4*)(Bt + bbase + (size_t)rr*K + k0 + cg*8);
    }
    __syncthreads();
    short8 af[4], bfr[4];
    for (int mt=0;mt<4;mt++) af[mt]  = *(const short8*)(&As[(wr*64+mt*16+l15)*40 + q*8]);
    for (int nt=0;nt<4;nt++) bfr[nt] = *(const short8*)(&Bs[(wc*64+nt*16+l15)*40 + q*8]);
    for (int mt=0;mt<4;mt++)
      for (int nt=0;nt<4;nt++)
        acc[mt][nt] = __builtin_amdgcn_mfma_f32_16x16x32_bf16(af[mt], bfr[nt], acc[mt][nt], 0,0,0);
    __syncthreads();
  }
  int rbase = q*4;
  for (int mt=0;mt<4;mt++) for (int nt=0;nt<4;nt++){
    for (int rr=0;rr<4;rr++){
      int gr = bm*128 + wr*64 + mt*16 + rbase + rr;
      int gc = bn*128 + wc*64 + nt*16 + l15;
      float v = acc[mt][nt][rr];
      if (epi == 0){
        ((float*)outp)[(size_t)gr*N + gc] = v;
      } else if (epi == 1){
        v += bias[gc];
        v = 0.5f*v*(1.f+erff(v*0.70710678118654752f));
        ((unsigned short*)outp)[(size_t)gr*N + gc] = f2b(v);
      } else if (epi == 2){
        v += bias[gc] + resid[(size_t)gr*N + gc];
        ((float*)outp)[(size_t)gr*N + gc] = v;
      } else {
        ((unsigned short*)outp)[(size_t)gr*N + gc] = f2b(v);
      }
    }
  }
}

// ---------------- conv + silu + dt/dA/dtx/B/C prep (per direction; zx is bf16) ----
__global__ __launch_bounds__(256) void prep_k(const unsigned short* __restrict__ zx,
    const float* __restrict__ conv_w, const float* __restrict__ conv_b,
    const float* __restrict__ dt_bias, const float* __restrict__ A_log,
    float* __restrict__ dAb, float* __restrict__ dtb,
    unsigned short* __restrict__ dtxb,
    unsigned short* __restrict__ Bb, unsigned short* __restrict__ Cb){
  int inst = blockIdx.x;
  int d = inst >> 13; int rem = inst & 8191;
  int b = rem >> 12; int s = rem & 4095;
  int tid = threadIdx.x;
  int t = d ? (LSEQ-1-s) : s;
  __shared__ float sdt[NHEADS];
  if (tid < NHEADS){
    float raw = b2f(zx[((size_t)b*LSEQ + t)*NPAD + (DINNER+CONVDIM) + tid]) + dt_bias[tid];
    float dt = (raw > 20.f) ? raw : log1pf(expf(raw));
    sdt[tid] = dt;
    size_t tok = (size_t)(d*BSZ+b)*LSEQ + s;
    dAb[tok*NHEADS + tid] = expf(-expf(A_log[tid]) * dt);
    dtb[tok*NHEADS + tid] = dt;
  }
  __syncthreads();
  size_t tok = (size_t)(d*BSZ+b)*LSEQ + s;
  for (int c = tid; c < CONVDIM; c += 256){
    float acc = conv_b[c];
    #pragma unroll
    for (int k=0;k<4;k++){
      int sig = s - 3 + k;
      if (sig >= 0){
        int tp = d ? (LSEQ-1-sig) : sig;
        acc += conv_w[k*CONVDIM + c] * b2f(zx[((size_t)b*LSEQ + tp)*NPAD + DINNER + c]);
      }
    }
    float v = acc / (1.f + expf(-acc));   // silu
    if (c < DINNER){
      dtxb[tok*DINNER + c] = f2b(v * sdt[c >> 6]);
    } else if (c < DINNER + DSTATE){
      Bb[tok*DSTATE + (c - DINNER)] = f2b(v);
    } else {
      Cb[tok*DSTATE + (c - DINNER - DSTATE)] = f2b(v);
    }
  }
}

// ---------------- pass 1: per-chunk local scan, state only ----------------
// grid (NCH, NHEADS, 2*BSZ); block = 64 (one wave); lane = p
__global__ __launch_bounds__(64) void scan_state_k(const float* __restrict__ dAb,
    const unsigned short* __restrict__ dtxb, const unsigned short* __restrict__ Bb,
    unsigned short* __restrict__ h_out, float* __restrict__ Pch){
  int ch = blockIdx.x, h = blockIdx.y, z = blockIdx.z;
  int p = threadIdx.x;
  size_t tokb = (size_t)z*LSEQ + (size_t)ch*LC;
  __shared__ float sdA[16];
  __shared__ __align__(16) float sdtx[16*64];
  __shared__ __align__(16) float sB[16*64];
  float hn[64];
  #pragma unroll
  for (int n=0;n<64;n++) hn[n]=0.f;
  float Pc = 1.f;
  for (int j0=0;j0<LC;j0+=16){
    if (p < 16) sdA[p] = dAb[(tokb + j0 + p)*NHEADS + h];
    for (int i=0;i<16;i++){
      sdtx[i*64+p] = b2f(dtxb[(tokb+j0+i)*DINNER + h*64 + p]);
      sB[i*64+p]   = b2f(Bb[(tokb+j0+i)*DSTATE + p]);
    }
    __syncthreads();
    for (int j=0;j<16;j++){
      float dA = sdA[j];
      float dtxp = sdtx[j*64+p];
      Pc *= dA;
      const float4* Bp = (const float4*)(&sB[j*64]);
      #pragma unroll
      for (int n4=0;n4<16;n4++){
        float4 Bv = Bp[n4];
        hn[n4*4+0] = hn[n4*4+0]*dA + dtxp*Bv.x;
        hn[n4*4+1] = hn[n4*4+1]*dA + dtxp*Bv.y;
        hn[n4*4+2] = hn[n4*4+2]*dA + dtxp*Bv.z;
        hn[n4*4+3] = hn[n4*4+3]*dA + dtxp*Bv.w;
      }
    }
    __syncthreads();
  }
  size_t hb = (((size_t)z*NHEADS + h)*NCH + ch)*4096;
  #pragma unroll
  for (int n=0;n<64;n++) h_out[hb + n*64 + p] = f2b(hn[n]);
  if (p==0) Pch[((size_t)z*NHEADS+h)*NCH + ch] = Pc;
}

// ---------------- pass 2: combine chunk states ----------------
// grid 64 = (z*NHEADS+h); thread owns 16 state elems
__global__ __launch_bounds__(256) void comb_k(const unsigned short* __restrict__ h_out,
    const float* __restrict__ Pch, unsigned short* __restrict__ h_in){
  int u = blockIdx.x; int tid = threadIdx.x;
  float hreg[16];
  #pragma unroll
  for (int k=0;k<16;k++) hreg[k]=0.f;
  for (int ch=0; ch<NCH; ch++){
    size_t base = ((size_t)u*NCH + ch)*4096;
    #pragma unroll
    for (int k=0;k<16;k++) h_in[base + tid + k*256] = f2b(hreg[k]);
    float P = Pch[(size_t)u*NCH + ch];
    #pragma unroll
    for (int k=0;k<16;k++) hreg[k] = hreg[k]*P + b2f(h_out[base + tid + k*256]);
  }
}

// ---------------- pass 3: replay with seeded state, emit y ----------------
__global__ __launch_bounds__(64) void scan_y_k(const float* __restrict__ dAb,
    const unsigned short* __restrict__ dtxb, const unsigned short* __restrict__ Bb,
    const unsigned short* __restrict__ Cb, const float* __restrict__ dtb,
    const unsigned short* __restrict__ h_in, const float* __restrict__ Dh,
    unsigned short* __restrict__ y0, unsigned short* __restrict__ y1){
  int ch = blockIdx.x, h = blockIdx.y, z = blockIdx.z;
  int d = z >> 1, b = z & 1;
  int p = threadIdx.x;
  unsigned short* yb = d ? y1 : y0;
  size_t tokb = (size_t)z*LSEQ + (size_t)ch*LC;
  size_t ytokb = (size_t)b*LSEQ;
  float hn[64];
  size_t hb = (((size_t)z*NHEADS + h)*NCH + ch)*4096;
  #pragma unroll
  for (int n=0;n<64;n++) hn[n] = b2f(h_in[hb + n*64 + p]);
  float Dv = Dh[h];
  __shared__ float sdA[16];
  __shared__ float sdti[16];
  __shared__ __align__(16) float sdtx[16*64];
  __shared__ __align__(16) float sB[16*64];
  __shared__ __align__(16) float sC[16*64];
  for (int j0=0;j0<LC;j0+=16){
    if (p < 16){
      sdA[p] = dAb[(tokb + j0 + p)*NHEADS + h];
      sdti[p] = 1.f / dtb[(tokb + j0 + p)*NHEADS + h];
    }
    for (int i=0;i<16;i++){
      sdtx[i*64+p] = b2f(dtxb[(tokb+j0+i)*DINNER + h*64 + p]);
      sB[i*64+p]   = b2f(Bb[(tokb+j0+i)*DSTATE + p]);
      sC[i*64+p]   = b2f(Cb[(tokb+j0+i)*DSTATE + p]);
    }
    __syncthreads();
    for (int j=0;j<16;j++){
      float dA = sdA[j];
      float dtxp = sdtx[j*64+p];
      const float4* Bp = (const float4*)(&sB[j*64]);
      const float4* Cp = (const float4*)(&sC[j*64]);
      float ya=0.f, yb_=0.f, yc=0.f, yd=0.f;
      #pragma unroll
      for (int n4=0;n4<16;n4++){
        float4 Bv = Bp[n4];
        float4 Cv = Cp[n4];
        float h0 = hn[n4*4+0]*dA + dtxp*Bv.x; hn[n4*4+0]=h0; ya += h0*Cv.x;
        float h1 = hn[n4*4+1]*dA + dtxp*Bv.y; hn[n4*4+1]=h1; yb_ += h1*Cv.y;
        float h2 = hn[n4*4+2]*dA + dtxp*Bv.z; hn[n4*4+2]=h2; yc += h2*Cv.z;
        float h3 = hn[n4*4+3]*dA + dtxp*Bv.w; hn[n4*4+3]=h3; yd += h3*Cv.w;
      }
      float y = (ya+yb_)+(yc+yd);
      y += Dv * (dtxp * sdti[j]);            // D * xh, xh = dtx/dt
      int t = ch*LC + j0 + j;
      int tph = d ? (LSEQ-1-t) : t;
      yb[(ytokb + tph)*DINNER + h*64 + p] = f2b(y);
    }
    __syncthreads();
  }
}

// ---------------- gate: g=y*silu(z), per-dir rmsnorm, sum, ->bf16 ----------------
__global__ __launch_bounds__(256) void gate_k(const unsigned short* __restrict__ y0,
    const unsigned short* __restrict__ y1, const unsigned short* __restrict__ zx,
    const float* __restrict__ mnw, unsigned short* __restrict__ gsum){
  int tok = blockIdx.x; int tid = threadIdx.x;
  __shared__ float g0s[DINNER], g1s[DINNER];
  float ss0 = 0.f, ss1 = 0.f;
  for (int i=0;i<4;i++){
    int c = tid + i*256;
    float z = b2f(zx[(size_t)tok*NPAD + c]);
    float sz = z / (1.f + expf(-z));
    float g0 = b2f(y0[(size_t)tok*DINNER + c]) * sz;
    float g1 = b2f(y1[(size_t)tok*DINNER + c]) * sz;
    g0s[c] = g0; g1s[c] = g1;
    ss0 += g0*g0; ss1 += g1*g1;
  }
  for (int m=32;m>=1;m>>=1){ ss0 += __shfl_xor(ss0,m); ss1 += __shfl_xor(ss1,m); }
  __shared__ float w0[4], w1[4];
  int wave = tid>>6, lane = tid&63;
  if (lane==0){ w0[wave]=ss0; w1[wave]=ss1; }
  __syncthreads();
  ss0 = w0[0]+w0[1]+w0[2]+w0[3];
  ss1 = w1[0]+w1[1]+w1[2]+w1[3];
  float r0 = rsqrtf(ss0*(1.f/DINNER) + 1e-5f);
  float r1 = rsqrtf(ss1*(1.f/DINNER) + 1e-5f);
  for (int i=0;i<4;i++){
    int c = tid + i*256;
    gsum[(size_t)tok*DINNER + c] = f2b((g0s[c]*r0 + g1s[c]*r1) * mnw[c]);
  }
}

extern "C" void kernel_launch(void* const* d_in, const int* in_sizes, int n_in,
                              void* d_out, int out_size, void* d_ws, size_t ws_size,
                              hipStream_t stream){
  const float* x       = (const float*)d_in[0];
  const float* nin_w   = (const float*)d_in[1];
  const float* nin_b   = (const float*)d_in[2];
  const float* nout_w  = (const float*)d_in[3];
  const float* nout_b  = (const float*)d_in[4];
  const float* in_w    = (const float*)d_in[5];
  const float* conv_w  = (const float*)d_in[6];
  const float* conv_b  = (const float*)d_in[7];
  const float* dt_bias = (const float*)d_in[8];
  const float* A_log   = (const float*)d_in[9];
  const float* D_h     = (const float*)d_in[10];
  const float* mnorm_w = (const float*)d_in[11];
  const float* out_w   = (const float*)d_in[12];
  const float* ff_w1   = (const float*)d_in[13];
  const float* ff_b1   = (const float*)d_in[14];
  const float* ff_w2   = (const float*)d_in[15];
  const float* ff_b2   = (const float*)d_in[16];
  float* out = (float*)d_out;

  char* ws = (char*)d_ws;
  size_t off = 0;
  auto alloc = [&](size_t bytes)->char*{
    char* p = ws + off; off = (off + bytes + 255) & ~(size_t)255; return p; };
  unsigned short* xn_bf = (unsigned short*)alloc((size_t)NTOK*DMODEL*2);
  unsigned short* in_wT = (unsigned short*)alloc((size_t)NPAD*DMODEL*2);
  unsigned short* out_wT= (unsigned short*)alloc((size_t)DMODEL*DINNER*2);
  unsigned short* w1T   = (unsigned short*)alloc((size_t)2048*DMODEL*2);
  unsigned short* w2T   = (unsigned short*)alloc((size_t)DMODEL*2048*2);
  unsigned short* zx    = (unsigned short*)alloc((size_t)NTOK*NPAD*2);
  float*          dAb   = (float*)alloc((size_t)2*NTOK*NHEADS*4);
  float*          dtb   = (float*)alloc((size_t)2*NTOK*NHEADS*4);
  unsigned short* Bb    = (unsigned short*)alloc((size_t)2*NTOK*DSTATE*2);
  unsigned short* Cb    = (unsigned short*)alloc((size_t)2*NTOK*DSTATE*2);
  unsigned short* dtxb  = (unsigned short*)alloc((size_t)2*NTOK*DINNER*2);
  unsigned short* y0    = (unsigned short*)alloc((size_t)NTOK*DINNER*2);
  unsigned short* y1    = (unsigned short*)alloc((size_t)NTOK*DINNER*2);
  unsigned short* h_in  = (unsigned short*)alloc((size_t)64*NCH*4096*2);
  float*          Pch   = (float*)alloc((size_t)64*NCH*4);
  size_t need = off;
  if (need > ws_size) return;  // fail absmax cleanly instead of faulting

  // aliases into sequentially-dead regions:
  unsigned short* h_out = y0;                          // written pass1, read comb; y0 written in pass3 (after comb)
  unsigned short* gsum  = dtxb;                        // dtxb dead after scan_y_k
  float* mpre = (float*)(dtxb + (size_t)NTOK*DINNER);  // 2nd half of dtxb
  unsigned short* m_bf  = y0;                          // y0 dead after gate_k
  unsigned short* h1    = zx;                          // zx dead after gate_k

  // weight transposes -> bf16 [N][K]
  wconv_t<<<dim3(NPAD/32,   DMODEL/32), 256, 0, stream>>>(in_w,  in_wT,  DMODEL, DPROJ,  NPAD);
  wconv_t<<<dim3(DMODEL/32, DINNER/32), 256, 0, stream>>>(out_w, out_wT, DINNER, DMODEL, DMODEL);
  wconv_t<<<dim3(2048/32,   DMODEL/32), 256, 0, stream>>>(ff_w1, w1T,    DMODEL, 2048,   2048);
  wconv_t<<<dim3(DMODEL/32, 2048/32),   256, 0, stream>>>(ff_w2, w2T,    2048,   DMODEL, DMODEL);
  // LN in -> bf16
  layernorm_k<<<NTOK, 256, 0, stream>>>(x, nin_w, nin_b, xn_bf);
  // in_proj (shared between directions) -> bf16 zx
  gemm_k<<<dim3(NPAD/128, NTOK/128), 256, 0, stream>>>(xn_bf, in_wT, zx, NTOK, NPAD, DMODEL, 3, nullptr, nullptr);
  // conv/silu/dt prep for both directions
  prep_k<<<2*NTOK, 256, 0, stream>>>(zx, conv_w, conv_b, dt_bias, A_log, dAb, dtb, dtxb, Bb, Cb);
  // chunked scan: local states -> combine -> replay with seeds
  scan_state_k<<<dim3(NCH, NHEADS, 2*BSZ), 64, 0, stream>>>(dAb, dtxb, Bb, h_out, Pch);
  comb_k<<<64, 256, 0, stream>>>(h_out, Pch, h_in);
  scan_y_k<<<dim3(NCH, NHEADS, 2*BSZ), 64, 0, stream>>>(dAb, dtxb, Bb, Cb, dtb, h_in, D_h, y0, y1);
  // gate + per-dir rmsnorm + sum (linearity: single out_proj GEMM)
  gate_k<<<NTOK, 256, 0, stream>>>(y0, y1, zx, mnorm_w, gsum);
  // out_proj -> f32 mpre
  gemm_k<<<dim3(DMODEL/128, NTOK/128), 256, 0, stream>>>(gsum, out_wT, mpre, NTOK, DMODEL, DINNER, 0, nullptr, nullptr);
  // LN out -> bf16
  layernorm_k<<<NTOK, 256, 0, stream>>>(mpre, nout_w, nout_b, m_bf);
  // ff1 + gelu -> bf16
  gemm_k<<<dim3(2048/128, NTOK/128), 256, 0, stream>>>(m_bf, w1T, h1, NTOK, 2048, DMODEL, 1, ff_b1, nullptr);
  // ff2 + bias + residual -> f32 out
  gemm_k<<<dim3(DMODEL/128, NTOK/128), 256, 0, stream>>>(h1, w2T, out, NTOK, DMODEL, 2048, 2, ff_b2, x);
}

// Round 4
// 626.596 us; speedup vs baseline: 2.9664x; 1.8856x over previous
//
#include <hip/hip_runtime.h>
#include <hip/hip_bf16.h>

#define LSEQ 4096
#define BSZ 2
#define DMODEL 512
#define DINNER 1024
#define DSTATE 64
#define NHEADS 16
#define CONVDIM 1152
#define DPROJ 2192
#define NPAD 2304
#define NTOK (BSZ*LSEQ)
#define LC 128
#define NCH (LSEQ/LC)

typedef __attribute__((ext_vector_type(8))) short short8;
typedef __attribute__((ext_vector_type(4))) float f32x4;

__device__ inline unsigned short f2b(float v){
  unsigned int u = __builtin_bit_cast(unsigned int, v);
  unsigned int r = (u + 0x7FFFu + ((u >> 16) & 1u)) >> 16;
  return (unsigned short)r;
}
__device__ inline float b2f(unsigned short u){
  unsigned int x = ((unsigned int)u) << 16;
  return __builtin_bit_cast(float, x);
}

// ---------------- weight transpose + f32->bf16 (src [K][Nsrc] -> dst [Npad][K]) ----
__global__ __launch_bounds__(256) void wconv_t(const float* __restrict__ src,
    unsigned short* __restrict__ dst, int K, int Nsrc, int Npad){
  __shared__ float t[32][33];
  int n0 = blockIdx.x*32, k0 = blockIdx.y*32;
  int tx = threadIdx.x & 31, ty = threadIdx.x >> 5;
  for (int i=0;i<4;i++){
    int k = k0 + ty + i*8; int n = n0 + tx;
    t[ty + i*8][tx] = (n < Nsrc) ? src[(size_t)k*Nsrc + n] : 0.f;
  }
  __syncthreads();
  for (int i=0;i<4;i++){
    int n = n0 + ty + i*8; int k = k0 + tx;
    if (n < Npad) dst[(size_t)n*K + k] = f2b(t[tx][ty + i*8]);
  }
}

// ---------------- layernorm over 512 cols (f32 in) -> bf16 ----------------
__global__ __launch_bounds__(256) void layernorm_k(const float* __restrict__ in,
    const float* __restrict__ w, const float* __restrict__ bb, unsigned short* __restrict__ out){
  int row = blockIdx.x; int tid = threadIdx.x;
  const float* r = in + (size_t)row*DMODEL;
  float v0 = r[tid], v1 = r[tid+256];
  float s = v0+v1, sq = v0*v0+v1*v1;
  for (int m=32;m>=1;m>>=1){ s += __shfl_xor(s,m); sq += __shfl_xor(sq,m); }
  __shared__ float ws_[4], wq_[4];
  int wave = tid>>6, lane = tid&63;
  if (lane==0){ ws_[wave]=s; wq_[wave]=sq; }
  __syncthreads();
  s = ws_[0]+ws_[1]+ws_[2]+ws_[3]; sq = wq_[0]+wq_[1]+wq_[2]+wq_[3];
  float mu = s * (1.f/DMODEL);
  float var = sq * (1.f/DMODEL) - mu*mu;
  float rs = rsqrtf(var + 1e-5f);
  out[(size_t)row*DMODEL + tid]     = f2b((v0-mu)*rs*w[tid] + bb[tid]);
  out[(size_t)row*DMODEL + tid+256] = f2b((v1-mu)*rs*w[tid+256] + bb[tid+256]);
}

// ---------------- bf16 MFMA GEMM: C[M,N] = A[M,K] @ Bt[N,K]^T ----------------
// epi 0: f32 plain ; 1: bf16 gelu(v+bias) ; 2: f32 v+bias+resid ; 3: bf16 plain
// Coalesced epilogue: per-wave 64x64 subtile staged through LDS (stride-65 pad),
// stores are full dwordx4 per lane (128B/row bf16, 256B/row f32 contiguous).
__global__ __launch_bounds__(256) void gemm_k(const unsigned short* __restrict__ A,
    const unsigned short* __restrict__ Bt, void* __restrict__ outp,
    int M, int N, int K, int epi, const float* __restrict__ bias, const float* __restrict__ resid){
  __shared__ __align__(16) unsigned short smem[2*128*40];
  unsigned short* As = smem;
  unsigned short* Bs = smem + 128*40;
  int tid = threadIdx.x;
  int lane = tid & 63, wave = tid >> 6;
  int wr = wave >> 1, wc = wave & 1;
  int l15 = lane & 15, q = lane >> 4;
  int bm = blockIdx.y, bn = blockIdx.x;
  f32x4 acc[4][4];
  for (int i=0;i<4;i++) for(int j=0;j<4;j++) acc[i][j] = (f32x4){0.f,0.f,0.f,0.f};
  const size_t abase = (size_t)bm*128*K;
  const size_t bbase = (size_t)bn*128*K;
  for (int k0 = 0; k0 < K; k0 += 32){
    for (int i=0;i<2;i++){
      int idx = tid + i*256; int rr = idx>>2, cg = idx&3;
      *(uint4*)(&As[rr*40 + cg*8]) = *(const uint4*)(A + abase + (size_t)rr*K + k0 + cg*8);
      *(uint4*)(&Bs[rr*40 + cg*8]) = *(const uint4*)(Bt + bbase + (size_t)rr*K + k0 + cg*8);
    }
    __syncthreads();
    short8 af[4], bfr[4];
    for (int mt=0;mt<4;mt++) af[mt]  = *(const short8*)(&As[(wr*64+mt*16+l15)*40 + q*8]);
    for (int nt=0;nt<4;nt++) bfr[nt] = *(const short8*)(&Bs[(wc*64+nt*16+l15)*40 + q*8]);
    for (int mt=0;mt<4;mt++)
      for (int nt=0;nt<4;nt++)
        acc[mt][nt] = __builtin_amdgcn_mfma_f32_16x16x32_bf16(af[mt], bfr[nt], acc[mt][nt], 0,0,0);
    __syncthreads();
  }
  // ---- coalesced epilogue ----
  // Each wave owns a 16-row x 65-float LDS scratch (4160B); 4 waves fit in smem (20480B).
  float* cbuf = ((float*)smem) + wave*1040;
  int rbase = q*4;
  int gr0t = bm*128 + wr*64;
  int gc0 = bn*128 + wc*64;
  for (int mt=0; mt<4; mt++){
    // scatter acc into LDS (row-major within the wave's 16x64 slab)
    for (int nt=0;nt<4;nt++)
      for (int rr=0;rr<4;rr++)
        cbuf[(rbase+rr)*65 + nt*16 + l15] = acc[mt][nt][rr];
    int gr0 = gr0t + mt*16;
    if (epi == 1 || epi == 3){
      int r8 = lane >> 3, c0 = (lane & 7)*8;
      #pragma unroll
      for (int h=0; h<2; h++){
        int row = h*8 + r8;
        float v[8];
        #pragma unroll
        for (int t=0;t<8;t++) v[t] = cbuf[row*65 + c0 + t];
        if (epi == 1){
          #pragma unroll
          for (int t=0;t<8;t++){
            float bv = v[t] + bias[gc0 + c0 + t];
            v[t] = 0.5f*bv*(1.f+erff(bv*0.70710678118654752f));
          }
        }
        uint4 pk;
        pk.x = (unsigned)f2b(v[0]) | ((unsigned)f2b(v[1])<<16);
        pk.y = (unsigned)f2b(v[2]) | ((unsigned)f2b(v[3])<<16);
        pk.z = (unsigned)f2b(v[4]) | ((unsigned)f2b(v[5])<<16);
        pk.w = (unsigned)f2b(v[6]) | ((unsigned)f2b(v[7])<<16);
        *(uint4*)((unsigned short*)outp + (size_t)(gr0+row)*N + gc0 + c0) = pk;
      }
    } else {
      int r4 = lane >> 4, c0 = (lane & 15)*4;
      #pragma unroll
      for (int h=0; h<4; h++){
        int row = h*4 + r4;
        float4 v;
        v.x = cbuf[row*65 + c0 + 0];
        v.y = cbuf[row*65 + c0 + 1];
        v.z = cbuf[row*65 + c0 + 2];
        v.w = cbuf[row*65 + c0 + 3];
        if (epi == 2){
          const float4 rv = *(const float4*)(resid + (size_t)(gr0+row)*N + gc0 + c0);
          v.x += bias[gc0+c0+0] + rv.x;
          v.y += bias[gc0+c0+1] + rv.y;
          v.z += bias[gc0+c0+2] + rv.z;
          v.w += bias[gc0+c0+3] + rv.w;
        }
        *(float4*)((float*)outp + (size_t)(gr0+row)*N + gc0 + c0) = v;
      }
    }
    // wave-private LDS slab; same-wave DS ops are pipe-ordered -> no barrier needed
  }
}

// ---------------- conv + silu + dt/dA/dtx/B/C prep (per direction; zx is bf16) ----
__global__ __launch_bounds__(256) void prep_k(const unsigned short* __restrict__ zx,
    const float* __restrict__ conv_w, const float* __restrict__ conv_b,
    const float* __restrict__ dt_bias, const float* __restrict__ A_log,
    float* __restrict__ dAb, float* __restrict__ dtb,
    unsigned short* __restrict__ dtxb,
    unsigned short* __restrict__ Bb, unsigned short* __restrict__ Cb){
  int inst = blockIdx.x;
  int d = inst >> 13; int rem = inst & 8191;
  int b = rem >> 12; int s = rem & 4095;
  int tid = threadIdx.x;
  int t = d ? (LSEQ-1-s) : s;
  __shared__ float sdt[NHEADS];
  if (tid < NHEADS){
    float raw = b2f(zx[((size_t)b*LSEQ + t)*NPAD + (DINNER+CONVDIM) + tid]) + dt_bias[tid];
    float dt = (raw > 20.f) ? raw : log1pf(expf(raw));
    sdt[tid] = dt;
    size_t tok = (size_t)(d*BSZ+b)*LSEQ + s;
    dAb[tok*NHEADS + tid] = expf(-expf(A_log[tid]) * dt);
    dtb[tok*NHEADS + tid] = dt;
  }
  __syncthreads();
  size_t tok = (size_t)(d*BSZ+b)*LSEQ + s;
  for (int c = tid; c < CONVDIM; c += 256){
    float acc = conv_b[c];
    #pragma unroll
    for (int k=0;k<4;k++){
      int sig = s - 3 + k;
      if (sig >= 0){
        int tp = d ? (LSEQ-1-sig) : sig;
        acc += conv_w[k*CONVDIM + c] * b2f(zx[((size_t)b*LSEQ + tp)*NPAD + DINNER + c]);
      }
    }
    float v = acc / (1.f + expf(-acc));   // silu
    if (c < DINNER){
      dtxb[tok*DINNER + c] = f2b(v * sdt[c >> 6]);
    } else if (c < DINNER + DSTATE){
      Bb[tok*DSTATE + (c - DINNER)] = f2b(v);
    } else {
      Cb[tok*DSTATE + (c - DINNER - DSTATE)] = f2b(v);
    }
  }
}

// ---------------- pass 1: per-chunk local scan, state only ----------------
// grid (NCH, NHEADS, 2*BSZ); block = 64 (one wave); lane = p
__global__ __launch_bounds__(64) void scan_state_k(const float* __restrict__ dAb,
    const unsigned short* __restrict__ dtxb, const unsigned short* __restrict__ Bb,
    unsigned short* __restrict__ h_out, float* __restrict__ Pch){
  int ch = blockIdx.x, h = blockIdx.y, z = blockIdx.z;
  int p = threadIdx.x;
  size_t tokb = (size_t)z*LSEQ + (size_t)ch*LC;
  __shared__ float sdA[16];
  __shared__ __align__(16) float sdtx[16*64];
  __shared__ __align__(16) float sB[16*64];
  float hn[64];
  #pragma unroll
  for (int n=0;n<64;n++) hn[n]=0.f;
  float Pc = 1.f;
  for (int j0=0;j0<LC;j0+=16){
    if (p < 16) sdA[p] = dAb[(tokb + j0 + p)*NHEADS + h];
    for (int i=0;i<16;i++){
      sdtx[i*64+p] = b2f(dtxb[(tokb+j0+i)*DINNER + h*64 + p]);
      sB[i*64+p]   = b2f(Bb[(tokb+j0+i)*DSTATE + p]);
    }
    __syncthreads();
    for (int j=0;j<16;j++){
      float dA = sdA[j];
      float dtxp = sdtx[j*64+p];
      Pc *= dA;
      const float4* Bp = (const float4*)(&sB[j*64]);
      #pragma unroll
      for (int n4=0;n4<16;n4++){
        float4 Bv = Bp[n4];
        hn[n4*4+0] = hn[n4*4+0]*dA + dtxp*Bv.x;
        hn[n4*4+1] = hn[n4*4+1]*dA + dtxp*Bv.y;
        hn[n4*4+2] = hn[n4*4+2]*dA + dtxp*Bv.z;
        hn[n4*4+3] = hn[n4*4+3]*dA + dtxp*Bv.w;
      }
    }
    __syncthreads();
  }
  size_t hb = (((size_t)z*NHEADS + h)*NCH + ch)*4096;
  #pragma unroll
  for (int n=0;n<64;n++) h_out[hb + n*64 + p] = f2b(hn[n]);
  if (p==0) Pch[((size_t)z*NHEADS+h)*NCH + ch] = Pc;
}

// ---------------- pass 2: combine chunk states ----------------
// grid 64 = (z*NHEADS+h); thread owns 16 state elems
__global__ __launch_bounds__(256) void comb_k(const unsigned short* __restrict__ h_out,
    const float* __restrict__ Pch, unsigned short* __restrict__ h_in){
  int u = blockIdx.x; int tid = threadIdx.x;
  float hreg[16];
  #pragma unroll
  for (int k=0;k<16;k++) hreg[k]=0.f;
  for (int ch=0; ch<NCH; ch++){
    size_t base = ((size_t)u*NCH + ch)*4096;
    #pragma unroll
    for (int k=0;k<16;k++) h_in[base + tid + k*256] = f2b(hreg[k]);
    float P = Pch[(size_t)u*NCH + ch];
    #pragma unroll
    for (int k=0;k<16;k++) hreg[k] = hreg[k]*P + b2f(h_out[base + tid + k*256]);
  }
}

// ---------------- pass 3: replay with seeded state, emit y ----------------
__global__ __launch_bounds__(64) void scan_y_k(const float* __restrict__ dAb,
    const unsigned short* __restrict__ dtxb, const unsigned short* __restrict__ Bb,
    const unsigned short* __restrict__ Cb, const float* __restrict__ dtb,
    const unsigned short* __restrict__ h_in, const float* __restrict__ Dh,
    unsigned short* __restrict__ y0, unsigned short* __restrict__ y1){
  int ch = blockIdx.x, h = blockIdx.y, z = blockIdx.z;
  int d = z >> 1, b = z & 1;
  int p = threadIdx.x;
  unsigned short* yb = d ? y1 : y0;
  size_t tokb = (size_t)z*LSEQ + (size_t)ch*LC;
  size_t ytokb = (size_t)b*LSEQ;
  float hn[64];
  size_t hb = (((size_t)z*NHEADS + h)*NCH + ch)*4096;
  #pragma unroll
  for (int n=0;n<64;n++) hn[n] = b2f(h_in[hb + n*64 + p]);
  float Dv = Dh[h];
  __shared__ float sdA[16];
  __shared__ float sdti[16];
  __shared__ __align__(16) float sdtx[16*64];
  __shared__ __align__(16) float sB[16*64];
  __shared__ __align__(16) float sC[16*64];
  for (int j0=0;j0<LC;j0+=16){
    if (p < 16){
      sdA[p] = dAb[(tokb + j0 + p)*NHEADS + h];
      sdti[p] = 1.f / dtb[(tokb + j0 + p)*NHEADS + h];
    }
    for (int i=0;i<16;i++){
      sdtx[i*64+p] = b2f(dtxb[(tokb+j0+i)*DINNER + h*64 + p]);
      sB[i*64+p]   = b2f(Bb[(tokb+j0+i)*DSTATE + p]);
      sC[i*64+p]   = b2f(Cb[(tokb+j0+i)*DSTATE + p]);
    }
    __syncthreads();
    for (int j=0;j<16;j++){
      float dA = sdA[j];
      float dtxp = sdtx[j*64+p];
      const float4* Bp = (const float4*)(&sB[j*64]);
      const float4* Cp = (const float4*)(&sC[j*64]);
      float ya=0.f, yb_=0.f, yc=0.f, yd=0.f;
      #pragma unroll
      for (int n4=0;n4<16;n4++){
        float4 Bv = Bp[n4];
        float4 Cv = Cp[n4];
        float h0 = hn[n4*4+0]*dA + dtxp*Bv.x; hn[n4*4+0]=h0; ya += h0*Cv.x;
        float h1 = hn[n4*4+1]*dA + dtxp*Bv.y; hn[n4*4+1]=h1; yb_ += h1*Cv.y;
        float h2 = hn[n4*4+2]*dA + dtxp*Bv.z; hn[n4*4+2]=h2; yc += h2*Cv.z;
        float h3 = hn[n4*4+3]*dA + dtxp*Bv.w; hn[n4*4+3]=h3; yd += h3*Cv.w;
      }
      float y = (ya+yb_)+(yc+yd);
      y += Dv * (dtxp * sdti[j]);            // D * xh, xh = dtx/dt
      int t = ch*LC + j0 + j;
      int tph = d ? (LSEQ-1-t) : t;
      yb[(ytokb + tph)*DINNER + h*64 + p] = f2b(y);
    }
    __syncthreads();
  }
}

// ---------------- gate: g=y*silu(z), per-dir rmsnorm, sum, ->bf16 ----------------
__global__ __launch_bounds__(256) void gate_k(const unsigned short* __restrict__ y0,
    const unsigned short* __restrict__ y1, const unsigned short* __restrict__ zx,
    const float* __restrict__ mnw, unsigned short* __restrict__ gsum){
  int tok = blockIdx.x; int tid = threadIdx.x;
  __shared__ float g0s[DINNER], g1s[DINNER];
  float ss0 = 0.f, ss1 = 0.f;
  for (int i=0;i<4;i++){
    int c = tid + i*256;
    float z = b2f(zx[(size_t)tok*NPAD + c]);
    float sz = z / (1.f + expf(-z));
    float g0 = b2f(y0[(size_t)tok*DINNER + c]) * sz;
    float g1 = b2f(y1[(size_t)tok*DINNER + c]) * sz;
    g0s[c] = g0; g1s[c] = g1;
    ss0 += g0*g0; ss1 += g1*g1;
  }
  for (int m=32;m>=1;m>>=1){ ss0 += __shfl_xor(ss0,m); ss1 += __shfl_xor(ss1,m); }
  __shared__ float w0[4], w1[4];
  int wave = tid>>6, lane = tid&63;
  if (lane==0){ w0[wave]=ss0; w1[wave]=ss1; }
  __syncthreads();
  ss0 = w0[0]+w0[1]+w0[2]+w0[3];
  ss1 = w1[0]+w1[1]+w1[2]+w1[3];
  float r0 = rsqrtf(ss0*(1.f/DINNER) + 1e-5f);
  float r1 = rsqrtf(ss1*(1.f/DINNER) + 1e-5f);
  for (int i=0;i<4;i++){
    int c = tid + i*256;
    gsum[(size_t)tok*DINNER + c] = f2b((g0s[c]*r0 + g1s[c]*r1) * mnw[c]);
  }
}

extern "C" void kernel_launch(void* const* d_in, const int* in_sizes, int n_in,
                              void* d_out, int out_size, void* d_ws, size_t ws_size,
                              hipStream_t stream){
  const float* x       = (const float*)d_in[0];
  const float* nin_w   = (const float*)d_in[1];
  const float* nin_b   = (const float*)d_in[2];
  const float* nout_w  = (const float*)d_in[3];
  const float* nout_b  = (const float*)d_in[4];
  const float* in_w    = (const float*)d_in[5];
  const float* conv_w  = (const float*)d_in[6];
  const float* conv_b  = (const float*)d_in[7];
  const float* dt_bias = (const float*)d_in[8];
  const float* A_log   = (const float*)d_in[9];
  const float* D_h     = (const float*)d_in[10];
  const float* mnorm_w = (const float*)d_in[11];
  const float* out_w   = (const float*)d_in[12];
  const float* ff_w1   = (const float*)d_in[13];
  const float* ff_b1   = (const float*)d_in[14];
  const float* ff_w2   = (const float*)d_in[15];
  const float* ff_b2   = (const float*)d_in[16];
  float* out = (float*)d_out;

  char* ws = (char*)d_ws;
  size_t off = 0;
  auto alloc = [&](size_t bytes)->char*{
    char* p = ws + off; off = (off + bytes + 255) & ~(size_t)255; return p; };
  unsigned short* xn_bf = (unsigned short*)alloc((size_t)NTOK*DMODEL*2);
  unsigned short* in_wT = (unsigned short*)alloc((size_t)NPAD*DMODEL*2);
  unsigned short* out_wT= (unsigned short*)alloc((size_t)DMODEL*DINNER*2);
  unsigned short* w1T   = (unsigned short*)alloc((size_t)2048*DMODEL*2);
  unsigned short* w2T   = (unsigned short*)alloc((size_t)DMODEL*2048*2);
  unsigned short* zx    = (unsigned short*)alloc((size_t)NTOK*NPAD*2);
  float*          dAb   = (float*)alloc((size_t)2*NTOK*NHEADS*4);
  float*          dtb   = (float*)alloc((size_t)2*NTOK*NHEADS*4);
  unsigned short* Bb    = (unsigned short*)alloc((size_t)2*NTOK*DSTATE*2);
  unsigned short* Cb    = (unsigned short*)alloc((size_t)2*NTOK*DSTATE*2);
  unsigned short* dtxb  = (unsigned short*)alloc((size_t)2*NTOK*DINNER*2);
  unsigned short* y0    = (unsigned short*)alloc((size_t)NTOK*DINNER*2);
  unsigned short* y1    = (unsigned short*)alloc((size_t)NTOK*DINNER*2);
  unsigned short* h_in  = (unsigned short*)alloc((size_t)64*NCH*4096*2);
  float*          Pch   = (float*)alloc((size_t)64*NCH*4);
  size_t need = off;
  if (need > ws_size) return;  // fail absmax cleanly instead of faulting

  // aliases into sequentially-dead regions:
  unsigned short* h_out = y0;                          // written pass1, read comb; y0 written in pass3 (after comb)
  unsigned short* gsum  = dtxb;                        // dtxb dead after scan_y_k
  float* mpre = (float*)(dtxb + (size_t)NTOK*DINNER);  // 2nd half of dtxb
  unsigned short* m_bf  = y0;                          // y0 dead after gate_k
  unsigned short* h1    = zx;                          // zx dead after gate_k

  // weight transposes -> bf16 [N][K]
  wconv_t<<<dim3(NPAD/32,   DMODEL/32), 256, 0, stream>>>(in_w,  in_wT,  DMODEL, DPROJ,  NPAD);
  wconv_t<<<dim3(DMODEL/32, DINNER/32), 256, 0, stream>>>(out_w, out_wT, DINNER, DMODEL, DMODEL);
  wconv_t<<<dim3(2048/32,   DMODEL/32), 256, 0, stream>>>(ff_w1, w1T,    DMODEL, 2048,   2048);
  wconv_t<<<dim3(DMODEL/32, 2048/32),   256, 0, stream>>>(ff_w2, w2T,    2048,   DMODEL, DMODEL);
  // LN in -> bf16
  layernorm_k<<<NTOK, 256, 0, stream>>>(x, nin_w, nin_b, xn_bf);
  // in_proj (shared between directions) -> bf16 zx
  gemm_k<<<dim3(NPAD/128, NTOK/128), 256, 0, stream>>>(xn_bf, in_wT, zx, NTOK, NPAD, DMODEL, 3, nullptr, nullptr);
  // conv/silu/dt prep for both directions
  prep_k<<<2*NTOK, 256, 0, stream>>>(zx, conv_w, conv_b, dt_bias, A_log, dAb, dtb, dtxb, Bb, Cb);
  // chunked scan: local states -> combine -> replay with seeds
  scan_state_k<<<dim3(NCH, NHEADS, 2*BSZ), 64, 0, stream>>>(dAb, dtxb, Bb, h_out, Pch);
  comb_k<<<64, 256, 0, stream>>>(h_out, Pch, h_in);
  scan_y_k<<<dim3(NCH, NHEADS, 2*BSZ), 64, 0, stream>>>(dAb, dtxb, Bb, Cb, dtb, h_in, D_h, y0, y1);
  // gate + per-dir rmsnorm + sum (linearity: single out_proj GEMM)
  gate_k<<<NTOK, 256, 0, stream>>>(y0, y1, zx, mnorm_w, gsum);
  // out_proj -> f32 mpre
  gemm_k<<<dim3(DMODEL/128, NTOK/128), 256, 0, stream>>>(gsum, out_wT, mpre, NTOK, DMODEL, DINNER, 0, nullptr, nullptr);
  // LN out -> bf16
  layernorm_k<<<NTOK, 256, 0, stream>>>(mpre, nout_w, nout_b, m_bf);
  // ff1 + gelu -> bf16
  gemm_k<<<dim3(2048/128, NTOK/128), 256, 0, stream>>>(m_bf, w1T, h1, NTOK, 2048, DMODEL, 1, ff_b1, nullptr);
  // ff2 + bias + residual -> f32 out
  gemm_k<<<dim3(DMODEL/128, NTOK/128), 256, 0, stream>>>(h1, w2T, out, NTOK, DMODEL, 2048, 2, ff_b2, x);
}

// Round 5
// 613.945 us; speedup vs baseline: 3.0275x; 1.0206x over previous
//
#include <hip/hip_runtime.h>
#include <hip/hip_bf16.h>

#define LSEQ 4096
#define BSZ 2
#define DMODEL 512
#define DINNER 1024
#define DSTATE 64
#define NHEADS 16
#define CONVDIM 1152
#define DPROJ 2192
#define NPAD 2304
#define NTOK (BSZ*LSEQ)
#define LC 64
#define NCH (LSEQ/LC)

typedef __attribute__((ext_vector_type(8))) short short8;
typedef __attribute__((ext_vector_type(4))) float f32x4;

__device__ inline unsigned short f2b(float v){
  unsigned int u = __builtin_bit_cast(unsigned int, v);
  unsigned int r = (u + 0x7FFFu + ((u >> 16) & 1u)) >> 16;
  return (unsigned short)r;
}
__device__ inline float b2f(unsigned short u){
  unsigned int x = ((unsigned int)u) << 16;
  return __builtin_bit_cast(float, x);
}

// ---------------- weight transpose + f32->bf16 (src [K][Nsrc] -> dst [Npad][K]) ----
__global__ __launch_bounds__(256) void wconv_t(const float* __restrict__ src,
    unsigned short* __restrict__ dst, int K, int Nsrc, int Npad){
  __shared__ float t[32][33];
  int n0 = blockIdx.x*32, k0 = blockIdx.y*32;
  int tx = threadIdx.x & 31, ty = threadIdx.x >> 5;
  for (int i=0;i<4;i++){
    int k = k0 + ty + i*8; int n = n0 + tx;
    t[ty + i*8][tx] = (n < Nsrc) ? src[(size_t)k*Nsrc + n] : 0.f;
  }
  __syncthreads();
  for (int i=0;i<4;i++){
    int n = n0 + ty + i*8; int k = k0 + tx;
    if (n < Npad) dst[(size_t)n*K + k] = f2b(t[tx][ty + i*8]);
  }
}

// ---------------- layernorm over 512 cols (f32 in) -> bf16 ----------------
__global__ __launch_bounds__(256) void layernorm_k(const float* __restrict__ in,
    const float* __restrict__ w, const float* __restrict__ bb, unsigned short* __restrict__ out){
  int row = blockIdx.x; int tid = threadIdx.x;
  const float* r = in + (size_t)row*DMODEL;
  float v0 = r[tid], v1 = r[tid+256];
  float s = v0+v1, sq = v0*v0+v1*v1;
  for (int m=32;m>=1;m>>=1){ s += __shfl_xor(s,m); sq += __shfl_xor(sq,m); }
  __shared__ float ws_[4], wq_[4];
  int wave = tid>>6, lane = tid&63;
  if (lane==0){ ws_[wave]=s; wq_[wave]=sq; }
  __syncthreads();
  s = ws_[0]+ws_[1]+ws_[2]+ws_[3]; sq = wq_[0]+wq_[1]+wq_[2]+wq_[3];
  float mu = s * (1.f/DMODEL);
  float var = sq * (1.f/DMODEL) - mu*mu;
  float rs = rsqrtf(var + 1e-5f);
  out[(size_t)row*DMODEL + tid]     = f2b((v0-mu)*rs*w[tid] + bb[tid]);
  out[(size_t)row*DMODEL + tid+256] = f2b((v1-mu)*rs*w[tid+256] + bb[tid+256]);
}

// ---------------- bf16 MFMA GEMM: C[M,N] = A[M,K] @ Bt[N,K]^T ----------------
// epi 0: f32 plain ; 1: bf16 gelu(v+bias) ; 2: f32 v+bias+resid ; 3: bf16 plain
__global__ __launch_bounds__(256) void gemm_k(const unsigned short* __restrict__ A,
    const unsigned short* __restrict__ Bt, void* __restrict__ outp,
    int M, int N, int K, int epi, const float* __restrict__ bias, const float* __restrict__ resid){
  __shared__ __align__(16) unsigned short smem[2*128*40];
  unsigned short* As = smem;
  unsigned short* Bs = smem + 128*40;
  int tid = threadIdx.x;
  int lane = tid & 63, wave = tid >> 6;
  int wr = wave >> 1, wc = wave & 1;
  int l15 = lane & 15, q = lane >> 4;
  int bm = blockIdx.y, bn = blockIdx.x;
  f32x4 acc[4][4];
  for (int i=0;i<4;i++) for(int j=0;j<4;j++) acc[i][j] = (f32x4){0.f,0.f,0.f,0.f};
  const size_t abase = (size_t)bm*128*K;
  const size_t bbase = (size_t)bn*128*K;
  for (int k0 = 0; k0 < K; k0 += 32){
    for (int i=0;i<2;i++){
      int idx = tid + i*256; int rr = idx>>2, cg = idx&3;
      *(uint4*)(&As[rr*40 + cg*8]) = *(const uint4*)(A + abase + (size_t)rr*K + k0 + cg*8);
      *(uint4*)(&Bs[rr*40 + cg*8]) = *(const uint4*)(Bt + bbase + (size_t)rr*K + k0 + cg*8);
    }
    __syncthreads();
    short8 af[4], bfr[4];
    for (int mt=0;mt<4;mt++) af[mt]  = *(const short8*)(&As[(wr*64+mt*16+l15)*40 + q*8]);
    for (int nt=0;nt<4;nt++) bfr[nt] = *(const short8*)(&Bs[(wc*64+nt*16+l15)*40 + q*8]);
    for (int mt=0;mt<4;mt++)
      for (int nt=0;nt<4;nt++)
        acc[mt][nt] = __builtin_amdgcn_mfma_f32_16x16x32_bf16(af[mt], bfr[nt], acc[mt][nt], 0,0,0);
    __syncthreads();
  }
  // ---- coalesced epilogue (per-wave 16x65-f32 LDS slab) ----
  float* cbuf = ((float*)smem) + wave*1040;
  int rbase = q*4;
  int gr0t = bm*128 + wr*64;
  int gc0 = bn*128 + wc*64;
  for (int mt=0; mt<4; mt++){
    for (int nt=0;nt<4;nt++)
      for (int rr=0;rr<4;rr++)
        cbuf[(rbase+rr)*65 + nt*16 + l15] = acc[mt][nt][rr];
    int gr0 = gr0t + mt*16;
    if (epi == 1 || epi == 3){
      int r8 = lane >> 3, c0 = (lane & 7)*8;
      #pragma unroll
      for (int h=0; h<2; h++){
        int row = h*8 + r8;
        float v[8];
        #pragma unroll
        for (int t=0;t<8;t++) v[t] = cbuf[row*65 + c0 + t];
        if (epi == 1){
          #pragma unroll
          for (int t=0;t<8;t++){
            float bv = v[t] + bias[gc0 + c0 + t];
            v[t] = 0.5f*bv*(1.f+erff(bv*0.70710678118654752f));
          }
        }
        uint4 pk;
        pk.x = (unsigned)f2b(v[0]) | ((unsigned)f2b(v[1])<<16);
        pk.y = (unsigned)f2b(v[2]) | ((unsigned)f2b(v[3])<<16);
        pk.z = (unsigned)f2b(v[4]) | ((unsigned)f2b(v[5])<<16);
        pk.w = (unsigned)f2b(v[6]) | ((unsigned)f2b(v[7])<<16);
        *(uint4*)((unsigned short*)outp + (size_t)(gr0+row)*N + gc0 + c0) = pk;
      }
    } else {
      int r4 = lane >> 4, c0 = (lane & 15)*4;
      #pragma unroll
      for (int h=0; h<4; h++){
        int row = h*4 + r4;
        float4 v;
        v.x = cbuf[row*65 + c0 + 0];
        v.y = cbuf[row*65 + c0 + 1];
        v.z = cbuf[row*65 + c0 + 2];
        v.w = cbuf[row*65 + c0 + 3];
        if (epi == 2){
          const float4 rv = *(const float4*)(resid + (size_t)(gr0+row)*N + gc0 + c0);
          v.x += bias[gc0+c0+0] + rv.x;
          v.y += bias[gc0+c0+1] + rv.y;
          v.z += bias[gc0+c0+2] + rv.z;
          v.w += bias[gc0+c0+3] + rv.w;
        }
        *(float4*)((float*)outp + (size_t)(gr0+row)*N + gc0 + c0) = v;
      }
    }
  }
}

// ---------------- conv + silu + dt/dA/dtx/B/C prep; d==0 also compacts z ----
__global__ __launch_bounds__(256) void prep_k(const unsigned short* __restrict__ zx,
    const float* __restrict__ conv_w, const float* __restrict__ conv_b,
    const float* __restrict__ dt_bias, const float* __restrict__ A_log,
    float* __restrict__ dAb, float* __restrict__ dtb,
    unsigned short* __restrict__ dtxb,
    unsigned short* __restrict__ Bb, unsigned short* __restrict__ Cb,
    unsigned short* __restrict__ zcomp){
  int inst = blockIdx.x;
  int d = inst >> 13; int rem = inst & 8191;
  int b = rem >> 12; int s = rem & 4095;
  int tid = threadIdx.x;
  int t = d ? (LSEQ-1-s) : s;
  __shared__ float sdt[NHEADS];
  if (tid < NHEADS){
    float raw = b2f(zx[((size_t)b*LSEQ + t)*NPAD + (DINNER+CONVDIM) + tid]) + dt_bias[tid];
    float dt = (raw > 20.f) ? raw : log1pf(expf(raw));
    sdt[tid] = dt;
    size_t tok = (size_t)(d*BSZ+b)*LSEQ + s;
    dAb[tok*NHEADS + tid] = expf(-expf(A_log[tid]) * dt);
    dtb[tok*NHEADS + tid] = dt;
  }
  __syncthreads();
  size_t tok = (size_t)(d*BSZ+b)*LSEQ + s;
  for (int c = tid; c < CONVDIM; c += 256){
    float acc = conv_b[c];
    #pragma unroll
    for (int k=0;k<4;k++){
      int sig = s - 3 + k;
      if (sig >= 0){
        int tp = d ? (LSEQ-1-sig) : sig;
        acc += conv_w[k*CONVDIM + c] * b2f(zx[((size_t)b*LSEQ + tp)*NPAD + DINNER + c]);
      }
    }
    float v = acc / (1.f + expf(-acc));   // silu
    if (c < DINNER){
      dtxb[tok*DINNER + c] = f2b(v * sdt[c >> 6]);
    } else if (c < DINNER + DSTATE){
      Bb[tok*DSTATE + (c - DINNER)] = f2b(v);
    } else {
      Cb[tok*DSTATE + (c - DINNER - DSTATE)] = f2b(v);
    }
  }
  if (d == 0){  // compact z columns (zx region is recycled as h_in later)
    size_t ztok = (size_t)b*LSEQ + s;
    for (int c = tid; c < DINNER; c += 256)
      zcomp[ztok*DINNER + c] = zx[ztok*NPAD + c];
  }
}

// ---------------- pass 1: per-chunk local scan, state only ----------------
// grid (NCH/4, NHEADS, 2*BSZ); block = 4 waves, wave = one chunk; lane = p
__global__ __launch_bounds__(256) void scan_state_k(const float* __restrict__ dAb,
    const unsigned short* __restrict__ dtxb, const unsigned short* __restrict__ Bb,
    unsigned short* __restrict__ h_out, float* __restrict__ Pch){
  int wv = threadIdx.x >> 6, p = threadIdx.x & 63;
  int ch = blockIdx.x*4 + wv, h = blockIdx.y, z = blockIdx.z;
  size_t tokb = (size_t)z*LSEQ + (size_t)ch*LC;
  __shared__ float sdA[4][8];
  __shared__ __align__(16) float sdtx[4][8*64];
  __shared__ __align__(16) float sB[4][8*64];
  float* mydA = sdA[wv];
  float* mydtx = sdtx[wv];
  float* myB = sB[wv];
  float hn[64];
  #pragma unroll
  for (int n=0;n<64;n++) hn[n]=0.f;
  float Pc = 1.f;
  for (int j0=0;j0<LC;j0+=8){
    if (p < 8) mydA[p] = dAb[(tokb + j0 + p)*NHEADS + h];
    for (int i=0;i<8;i++){
      mydtx[i*64+p] = b2f(dtxb[(tokb+j0+i)*DINNER + h*64 + p]);
      myB[i*64+p]   = b2f(Bb[(tokb+j0+i)*DSTATE + p]);
    }
    // same-wave LDS: DS pipe is in-order per wave; no barrier needed
    for (int j=0;j<8;j++){
      float dA = mydA[j];
      float dtxp = mydtx[j*64+p];
      Pc *= dA;
      const float4* Bp = (const float4*)(&myB[j*64]);
      #pragma unroll
      for (int n4=0;n4<16;n4++){
        float4 Bv = Bp[n4];
        hn[n4*4+0] = hn[n4*4+0]*dA + dtxp*Bv.x;
        hn[n4*4+1] = hn[n4*4+1]*dA + dtxp*Bv.y;
        hn[n4*4+2] = hn[n4*4+2]*dA + dtxp*Bv.z;
        hn[n4*4+3] = hn[n4*4+3]*dA + dtxp*Bv.w;
      }
    }
  }
  size_t hb = (((size_t)z*NHEADS + h)*NCH + ch)*4096;
  #pragma unroll
  for (int n=0;n<64;n++) h_out[hb + n*64 + p] = f2b(hn[n]);
  if (p==0) Pch[((size_t)z*NHEADS+h)*NCH + ch] = Pc;
}

// ---------------- pass 2: combine chunk states ----------------
__global__ __launch_bounds__(256) void comb_k(const unsigned short* __restrict__ h_out,
    const float* __restrict__ Pch, unsigned short* __restrict__ h_in){
  int u = blockIdx.x; int tid = threadIdx.x;
  float hreg[16];
  #pragma unroll
  for (int k=0;k<16;k++) hreg[k]=0.f;
  for (int ch=0; ch<NCH; ch++){
    size_t base = ((size_t)u*NCH + ch)*4096;
    #pragma unroll
    for (int k=0;k<16;k++) h_in[base + tid + k*256] = f2b(hreg[k]);
    float P = Pch[(size_t)u*NCH + ch];
    #pragma unroll
    for (int k=0;k<16;k++) hreg[k] = hreg[k]*P + b2f(h_out[base + tid + k*256]);
  }
}

// ---------------- pass 3: replay with seeded state, emit y ----------------
// grid (NCH/4, NHEADS, 2*BSZ); block = 4 waves, wave = one chunk; lane = p
__global__ __launch_bounds__(256) void scan_y_k(const float* __restrict__ dAb,
    const unsigned short* __restrict__ dtxb, const unsigned short* __restrict__ Bb,
    const unsigned short* __restrict__ Cb, const float* __restrict__ dtb,
    const unsigned short* __restrict__ h_in, const float* __restrict__ Dh,
    unsigned short* __restrict__ y0, unsigned short* __restrict__ y1){
  int wv = threadIdx.x >> 6, p = threadIdx.x & 63;
  int ch = blockIdx.x*4 + wv, h = blockIdx.y, z = blockIdx.z;
  int d = z >> 1, b = z & 1;
  unsigned short* yb = d ? y1 : y0;
  size_t tokb = (size_t)z*LSEQ + (size_t)ch*LC;
  size_t ytokb = (size_t)b*LSEQ;
  float hn[64];
  size_t hb = (((size_t)z*NHEADS + h)*NCH + ch)*4096;
  #pragma unroll
  for (int n=0;n<64;n++) hn[n] = b2f(h_in[hb + n*64 + p]);
  float Dv = Dh[h];
  __shared__ float sdA[4][8];
  __shared__ float sdti[4][8];
  __shared__ __align__(16) float sdtx[4][8*64];
  __shared__ __align__(16) float sB[4][8*64];
  __shared__ __align__(16) float sC[4][8*64];
  float* mydA = sdA[wv]; float* mydti = sdti[wv];
  float* mydtx = sdtx[wv]; float* myB = sB[wv]; float* myC = sC[wv];
  for (int j0=0;j0<LC;j0+=8){
    if (p < 8){
      mydA[p]  = dAb[(tokb + j0 + p)*NHEADS + h];
      mydti[p] = 1.f / dtb[(tokb + j0 + p)*NHEADS + h];
    }
    for (int i=0;i<8;i++){
      mydtx[i*64+p] = b2f(dtxb[(tokb+j0+i)*DINNER + h*64 + p]);
      myB[i*64+p]   = b2f(Bb[(tokb+j0+i)*DSTATE + p]);
      myC[i*64+p]   = b2f(Cb[(tokb+j0+i)*DSTATE + p]);
    }
    // same-wave LDS: in-order DS pipe; no barrier needed
    for (int j=0;j<8;j++){
      float dA = mydA[j];
      float dtxp = mydtx[j*64+p];
      const float4* Bp = (const float4*)(&myB[j*64]);
      const float4* Cp = (const float4*)(&myC[j*64]);
      float ya=0.f, yb_=0.f, yc=0.f, yd=0.f;
      #pragma unroll
      for (int n4=0;n4<16;n4++){
        float4 Bv = Bp[n4];
        float4 Cv = Cp[n4];
        float h0 = hn[n4*4+0]*dA + dtxp*Bv.x; hn[n4*4+0]=h0; ya += h0*Cv.x;
        float h1 = hn[n4*4+1]*dA + dtxp*Bv.y; hn[n4*4+1]=h1; yb_ += h1*Cv.y;
        float h2 = hn[n4*4+2]*dA + dtxp*Bv.z; hn[n4*4+2]=h2; yc += h2*Cv.z;
        float h3 = hn[n4*4+3]*dA + dtxp*Bv.w; hn[n4*4+3]=h3; yd += h3*Cv.w;
      }
      float y = (ya+yb_)+(yc+yd);
      y += Dv * (dtxp * mydti[j]);           // D * xh, xh = dtx/dt
      int t = ch*LC + j0 + j;
      int tph = d ? (LSEQ-1-t) : t;
      yb[(ytokb + tph)*DINNER + h*64 + p] = f2b(y);
    }
  }
}

// ---------------- gate: g=y*silu(z), per-dir rmsnorm, sum, ->bf16 ----------------
__global__ __launch_bounds__(256) void gate_k(const unsigned short* __restrict__ y0,
    const unsigned short* __restrict__ y1, const unsigned short* __restrict__ zcomp,
    const float* __restrict__ mnw, unsigned short* __restrict__ gsum){
  int tok = blockIdx.x; int tid = threadIdx.x;
  __shared__ float g0s[DINNER], g1s[DINNER];
  float ss0 = 0.f, ss1 = 0.f;
  for (int i=0;i<4;i++){
    int c = tid + i*256;
    float z = b2f(zcomp[(size_t)tok*DINNER + c]);
    float sz = z / (1.f + expf(-z));
    float g0 = b2f(y0[(size_t)tok*DINNER + c]) * sz;
    float g1 = b2f(y1[(size_t)tok*DINNER + c]) * sz;
    g0s[c] = g0; g1s[c] = g1;
    ss0 += g0*g0; ss1 += g1*g1;
  }
  for (int m=32;m>=1;m>>=1){ ss0 += __shfl_xor(ss0,m); ss1 += __shfl_xor(ss1,m); }
  __shared__ float w0[4], w1[4];
  int wave = tid>>6, lane = tid&63;
  if (lane==0){ w0[wave]=ss0; w1[wave]=ss1; }
  __syncthreads();
  ss0 = w0[0]+w0[1]+w0[2]+w0[3];
  ss1 = w1[0]+w1[1]+w1[2]+w1[3];
  float r0 = rsqrtf(ss0*(1.f/DINNER) + 1e-5f);
  float r1 = rsqrtf(ss1*(1.f/DINNER) + 1e-5f);
  for (int i=0;i<4;i++){
    int c = tid + i*256;
    gsum[(size_t)tok*DINNER + c] = f2b((g0s[c]*r0 + g1s[c]*r1) * mnw[c]);
  }
}

extern "C" void kernel_launch(void* const* d_in, const int* in_sizes, int n_in,
                              void* d_out, int out_size, void* d_ws, size_t ws_size,
                              hipStream_t stream){
  const float* x       = (const float*)d_in[0];
  const float* nin_w   = (const float*)d_in[1];
  const float* nin_b   = (const float*)d_in[2];
  const float* nout_w  = (const float*)d_in[3];
  const float* nout_b  = (const float*)d_in[4];
  const float* in_w    = (const float*)d_in[5];
  const float* conv_w  = (const float*)d_in[6];
  const float* conv_b  = (const float*)d_in[7];
  const float* dt_bias = (const float*)d_in[8];
  const float* A_log   = (const float*)d_in[9];
  const float* D_h     = (const float*)d_in[10];
  const float* mnorm_w = (const float*)d_in[11];
  const float* out_w   = (const float*)d_in[12];
  const float* ff_w1   = (const float*)d_in[13];
  const float* ff_b1   = (const float*)d_in[14];
  const float* ff_w2   = (const float*)d_in[15];
  const float* ff_b2   = (const float*)d_in[16];
  float* out = (float*)d_out;

  char* ws = (char*)d_ws;
  size_t off = 0;
  auto alloc = [&](size_t bytes)->char*{
    char* p = ws + off; off = (off + bytes + 255) & ~(size_t)255; return p; };
  unsigned short* xn_bf = (unsigned short*)alloc((size_t)NTOK*DMODEL*2);
  unsigned short* in_wT = (unsigned short*)alloc((size_t)NPAD*DMODEL*2);
  unsigned short* out_wT= (unsigned short*)alloc((size_t)DMODEL*DINNER*2);
  unsigned short* w1T   = (unsigned short*)alloc((size_t)2048*DMODEL*2);
  unsigned short* w2T   = (unsigned short*)alloc((size_t)DMODEL*2048*2);
  unsigned short* zx    = (unsigned short*)alloc((size_t)NTOK*NPAD*2);      // 37.7 MB
  unsigned short* zcomp = (unsigned short*)alloc((size_t)NTOK*DINNER*2);    // 16.8 MB
  float*          dAb   = (float*)alloc((size_t)2*NTOK*NHEADS*4);
  float*          dtb   = (float*)alloc((size_t)2*NTOK*NHEADS*4);
  unsigned short* Bb    = (unsigned short*)alloc((size_t)2*NTOK*DSTATE*2);
  unsigned short* Cb    = (unsigned short*)alloc((size_t)2*NTOK*DSTATE*2);
  unsigned short* dtxb  = (unsigned short*)alloc((size_t)2*NTOK*DINNER*2);  // 33.6 MB
  unsigned short* y0    = (unsigned short*)alloc((size_t)NTOK*DINNER*2);    // 16.8 MB
  unsigned short* y1    = (unsigned short*)alloc((size_t)NTOK*DINNER*2);    // 16.8 MB (contig after y0)
  float*          Pch   = (float*)alloc((size_t)64*NCH*4);
  size_t need = off;
  if (need > ws_size) return;  // fail absmax cleanly instead of faulting

  // aliases into sequentially-dead regions:
  unsigned short* h_out = y0;                          // 33.55 MB = y0+y1 exactly; dead once comb_k reads it
  unsigned short* h_in  = zx;                          // zx dead after prep_k (z compacted to zcomp)
  unsigned short* gsum  = dtxb;                        // dtxb dead after scan_y_k
  float* mpre = (float*)(dtxb + (size_t)NTOK*DINNER);  // 2nd half of dtxb
  unsigned short* m_bf  = y0;                          // y0 dead after gate_k
  unsigned short* h1    = zx;                          // h_in dead after scan_y_k

  // weight transposes -> bf16 [N][K]
  wconv_t<<<dim3(NPAD/32,   DMODEL/32), 256, 0, stream>>>(in_w,  in_wT,  DMODEL, DPROJ,  NPAD);
  wconv_t<<<dim3(DMODEL/32, DINNER/32), 256, 0, stream>>>(out_w, out_wT, DINNER, DMODEL, DMODEL);
  wconv_t<<<dim3(2048/32,   DMODEL/32), 256, 0, stream>>>(ff_w1, w1T,    DMODEL, 2048,   2048);
  wconv_t<<<dim3(DMODEL/32, 2048/32),   256, 0, stream>>>(ff_w2, w2T,    2048,   DMODEL, DMODEL);
  // LN in -> bf16
  layernorm_k<<<NTOK, 256, 0, stream>>>(x, nin_w, nin_b, xn_bf);
  // in_proj (shared between directions) -> bf16 zx
  gemm_k<<<dim3(NPAD/128, NTOK/128), 256, 0, stream>>>(xn_bf, in_wT, zx, NTOK, NPAD, DMODEL, 3, nullptr, nullptr);
  // conv/silu/dt prep for both directions (+ z compaction)
  prep_k<<<2*NTOK, 256, 0, stream>>>(zx, conv_w, conv_b, dt_bias, A_log, dAb, dtb, dtxb, Bb, Cb, zcomp);
  // chunked scan: local states -> combine -> replay with seeds
  scan_state_k<<<dim3(NCH/4, NHEADS, 2*BSZ), 256, 0, stream>>>(dAb, dtxb, Bb, h_out, Pch);
  comb_k<<<64, 256, 0, stream>>>(h_out, Pch, h_in);
  scan_y_k<<<dim3(NCH/4, NHEADS, 2*BSZ), 256, 0, stream>>>(dAb, dtxb, Bb, Cb, dtb, h_in, D_h, y0, y1);
  // gate + per-dir rmsnorm + sum (linearity: single out_proj GEMM)
  gate_k<<<NTOK, 256, 0, stream>>>(y0, y1, zcomp, mnorm_w, gsum);
  // out_proj -> f32 mpre
  gemm_k<<<dim3(DMODEL/128, NTOK/128), 256, 0, stream>>>(gsum, out_wT, mpre, NTOK, DMODEL, DINNER, 0, nullptr, nullptr);
  // LN out -> bf16
  layernorm_k<<<NTOK, 256, 0, stream>>>(mpre, nout_w, nout_b, m_bf);
  // ff1 + gelu -> bf16
  gemm_k<<<dim3(2048/128, NTOK/128), 256, 0, stream>>>(m_bf, w1T, h1, NTOK, 2048, DMODEL, 1, ff_b1, nullptr);
  // ff2 + bias + residual -> f32 out
  gemm_k<<<dim3(DMODEL/128, NTOK/128), 256, 0, stream>>>(h1, w2T, out, NTOK, DMODEL, 2048, 2, ff_b2, x);
}

// Round 6
// 491.859 us; speedup vs baseline: 3.7790x; 1.2482x over previous
//
#include <hip/hip_runtime.h>
#include <hip/hip_bf16.h>

#define LSEQ 4096
#define BSZ 2
#define DMODEL 512
#define DINNER 1024
#define DSTATE 64
#define NHEADS 16
#define CONVDIM 1152
#define DPROJ 2192
#define NPAD 2304
#define NTOK (BSZ*LSEQ)
#define NCH 64   /* 64-token chunks */

typedef __attribute__((ext_vector_type(8))) short short8;
typedef __attribute__((ext_vector_type(4))) float f32x4;

__device__ inline unsigned short f2b(float v){
  unsigned int u = __builtin_bit_cast(unsigned int, v);
  unsigned int r = (u + 0x7FFFu + ((u >> 16) & 1u)) >> 16;
  return (unsigned short)r;
}
__device__ inline float b2f(unsigned short u){
  unsigned int x = ((unsigned int)u) << 16;
  return __builtin_bit_cast(float, x);
}

// ---------------- weight transpose + f32->bf16 (src [K][Nsrc] -> dst [Npad][K]) ----
__global__ __launch_bounds__(256) void wconv_t(const float* __restrict__ src,
    unsigned short* __restrict__ dst, int K, int Nsrc, int Npad){
  __shared__ float t[32][33];
  int n0 = blockIdx.x*32, k0 = blockIdx.y*32;
  int tx = threadIdx.x & 31, ty = threadIdx.x >> 5;
  for (int i=0;i<4;i++){
    int k = k0 + ty + i*8; int n = n0 + tx;
    t[ty + i*8][tx] = (n < Nsrc) ? src[(size_t)k*Nsrc + n] : 0.f;
  }
  __syncthreads();
  for (int i=0;i<4;i++){
    int n = n0 + ty + i*8; int k = k0 + tx;
    if (n < Npad) dst[(size_t)n*K + k] = f2b(t[tx][ty + i*8]);
  }
}

// ---------------- layernorm over 512 cols (f32 in) -> bf16 ----------------
__global__ __launch_bounds__(256) void layernorm_k(const float* __restrict__ in,
    const float* __restrict__ w, const float* __restrict__ bb, unsigned short* __restrict__ out){
  int row = blockIdx.x; int tid = threadIdx.x;
  const float* r = in + (size_t)row*DMODEL;
  float v0 = r[tid], v1 = r[tid+256];
  float s = v0+v1, sq = v0*v0+v1*v1;
  for (int m=32;m>=1;m>>=1){ s += __shfl_xor(s,m); sq += __shfl_xor(sq,m); }
  __shared__ float ws_[4], wq_[4];
  int wave = tid>>6, lane = tid&63;
  if (lane==0){ ws_[wave]=s; wq_[wave]=sq; }
  __syncthreads();
  s = ws_[0]+ws_[1]+ws_[2]+ws_[3]; sq = wq_[0]+wq_[1]+wq_[2]+wq_[3];
  float mu = s * (1.f/DMODEL);
  float var = sq * (1.f/DMODEL) - mu*mu;
  float rs = rsqrtf(var + 1e-5f);
  out[(size_t)row*DMODEL + tid]     = f2b((v0-mu)*rs*w[tid] + bb[tid]);
  out[(size_t)row*DMODEL + tid+256] = f2b((v1-mu)*rs*w[tid+256] + bb[tid+256]);
}

// ---------------- bf16 MFMA GEMM: C[M,N] = A[M,K] @ Bt[N,K]^T ----------------
// epi 0: f32 plain ; 1: bf16 gelu(v+bias) ; 2: f32 v+bias+resid ; 3: bf16 plain
__global__ __launch_bounds__(256) void gemm_k(const unsigned short* __restrict__ A,
    const unsigned short* __restrict__ Bt, void* __restrict__ outp,
    int M, int N, int K, int epi, const float* __restrict__ bias, const float* __restrict__ resid){
  __shared__ __align__(16) unsigned short smem[2*128*40];
  unsigned short* As = smem;
  unsigned short* Bs = smem + 128*40;
  int tid = threadIdx.x;
  int lane = tid & 63, wave = tid >> 6;
  int wr = wave >> 1, wc = wave & 1;
  int l15 = lane & 15, q = lane >> 4;
  int bm = blockIdx.y, bn = blockIdx.x;
  f32x4 acc[4][4];
  for (int i=0;i<4;i++) for(int j=0;j<4;j++) acc[i][j] = (f32x4){0.f,0.f,0.f,0.f};
  const size_t abase = (size_t)bm*128*K;
  const size_t bbase = (size_t)bn*128*K;
  for (int k0 = 0; k0 < K; k0 += 32){
    for (int i=0;i<2;i++){
      int idx = tid + i*256; int rr = idx>>2, cg = idx&3;
      *(uint4*)(&As[rr*40 + cg*8]) = *(const uint4*)(A + abase + (size_t)rr*K + k0 + cg*8);
      *(uint4*)(&Bs[rr*40 + cg*8]) = *(const uint4*)(Bt + bbase + (size_t)rr*K + k0 + cg*8);
    }
    __syncthreads();
    short8 af[4], bfr[4];
    for (int mt=0;mt<4;mt++) af[mt]  = *(const short8*)(&As[(wr*64+mt*16+l15)*40 + q*8]);
    for (int nt=0;nt<4;nt++) bfr[nt] = *(const short8*)(&Bs[(wc*64+nt*16+l15)*40 + q*8]);
    for (int mt=0;mt<4;mt++)
      for (int nt=0;nt<4;nt++)
        acc[mt][nt] = __builtin_amdgcn_mfma_f32_16x16x32_bf16(af[mt], bfr[nt], acc[mt][nt], 0,0,0);
    __syncthreads();
  }
  // ---- coalesced epilogue (per-wave 16x65-f32 LDS slab) ----
  float* cbuf = ((float*)smem) + wave*1040;
  int rbase = q*4;
  int gr0t = bm*128 + wr*64;
  int gc0 = bn*128 + wc*64;
  for (int mt=0; mt<4; mt++){
    for (int nt=0;nt<4;nt++)
      for (int rr=0;rr<4;rr++)
        cbuf[(rbase+rr)*65 + nt*16 + l15] = acc[mt][nt][rr];
    int gr0 = gr0t + mt*16;
    if (epi == 1 || epi == 3){
      int r8 = lane >> 3, c0 = (lane & 7)*8;
      #pragma unroll
      for (int h=0; h<2; h++){
        int row = h*8 + r8;
        float v[8];
        #pragma unroll
        for (int t=0;t<8;t++) v[t] = cbuf[row*65 + c0 + t];
        if (epi == 1){
          #pragma unroll
          for (int t=0;t<8;t++){
            float bv = v[t] + bias[gc0 + c0 + t];
            v[t] = 0.5f*bv*(1.f+erff(bv*0.70710678118654752f));
          }
        }
        uint4 pk;
        pk.x = (unsigned)f2b(v[0]) | ((unsigned)f2b(v[1])<<16);
        pk.y = (unsigned)f2b(v[2]) | ((unsigned)f2b(v[3])<<16);
        pk.z = (unsigned)f2b(v[4]) | ((unsigned)f2b(v[5])<<16);
        pk.w = (unsigned)f2b(v[6]) | ((unsigned)f2b(v[7])<<16);
        *(uint4*)((unsigned short*)outp + (size_t)(gr0+row)*N + gc0 + c0) = pk;
      }
    } else {
      int r4 = lane >> 4, c0 = (lane & 15)*4;
      #pragma unroll
      for (int h=0; h<4; h++){
        int row = h*4 + r4;
        float4 v;
        v.x = cbuf[row*65 + c0 + 0];
        v.y = cbuf[row*65 + c0 + 1];
        v.z = cbuf[row*65 + c0 + 2];
        v.w = cbuf[row*65 + c0 + 3];
        if (epi == 2){
          const float4 rv = *(const float4*)(resid + (size_t)(gr0+row)*N + gc0 + c0);
          v.x += bias[gc0+c0+0] + rv.x;
          v.y += bias[gc0+c0+1] + rv.y;
          v.z += bias[gc0+c0+2] + rv.z;
          v.w += bias[gc0+c0+3] + rv.w;
        }
        *(float4*)((float*)outp + (size_t)(gr0+row)*N + gc0 + c0) = v;
      }
    }
  }
}

// ---------------- conv + silu + dt/dA/dtx/B/C prep; d==0 also compacts z ----
__global__ __launch_bounds__(256) void prep_k(const unsigned short* __restrict__ zx,
    const float* __restrict__ conv_w, const float* __restrict__ conv_b,
    const float* __restrict__ dt_bias, const float* __restrict__ A_log,
    float* __restrict__ dAb, float* __restrict__ dtb,
    unsigned short* __restrict__ dtxb,
    unsigned short* __restrict__ Bb, unsigned short* __restrict__ Cb,
    unsigned short* __restrict__ zcomp){
  int inst = blockIdx.x;
  int d = inst >> 13; int rem = inst & 8191;
  int b = rem >> 12; int s = rem & 4095;
  int tid = threadIdx.x;
  int t = d ? (LSEQ-1-s) : s;
  __shared__ float sdt[NHEADS];
  if (tid < NHEADS){
    float raw = b2f(zx[((size_t)b*LSEQ + t)*NPAD + (DINNER+CONVDIM) + tid]) + dt_bias[tid];
    float dt = (raw > 20.f) ? raw : log1pf(expf(raw));
    sdt[tid] = dt;
    size_t tok = (size_t)(d*BSZ+b)*LSEQ + s;
    dAb[tok*NHEADS + tid] = expf(-expf(A_log[tid]) * dt);
    dtb[tok*NHEADS + tid] = dt;
  }
  __syncthreads();
  size_t tok = (size_t)(d*BSZ+b)*LSEQ + s;
  for (int c = tid; c < CONVDIM; c += 256){
    float acc = conv_b[c];
    #pragma unroll
    for (int k=0;k<4;k++){
      int sig = s - 3 + k;
      if (sig >= 0){
        int tp = d ? (LSEQ-1-sig) : sig;
        acc += conv_w[k*CONVDIM + c] * b2f(zx[((size_t)b*LSEQ + tp)*NPAD + DINNER + c]);
      }
    }
    float v = acc / (1.f + expf(-acc));   // silu
    if (c < DINNER){
      dtxb[tok*DINNER + c] = f2b(v * sdt[c >> 6]);
    } else if (c < DINNER + DSTATE){
      Bb[tok*DSTATE + (c - DINNER)] = f2b(v);
    } else {
      Cb[tok*DSTATE + (c - DINNER - DSTATE)] = f2b(v);
    }
  }
  if (d == 0){  // compact z columns (zx region recycled as hbuf later)
    size_t ztok = (size_t)b*LSEQ + s;
    for (int c = tid; c < DINNER; c += 256)
      zcomp[ztok*DINNER + c] = zx[ztok*NPAD + c];
  }
}

// ---- 64x64x64 bf16 GEMM on one wave: D += A(S-rows m, k contiguous) * B(S-rows n)^T
__device__ inline void gemm64(const unsigned short* Ab, const unsigned short* Bb_,
                              int l15, int q, f32x4 acc[4][4]){
  #pragma unroll
  for (int ks=0; ks<2; ks++){
    short8 af[4], bf4[4];
    #pragma unroll
    for (int mt=0;mt<4;mt++) af[mt]  = *(const short8*)(Ab  + (mt*16+l15)*72 + ks*32 + q*8);
    #pragma unroll
    for (int nt=0;nt<4;nt++) bf4[nt] = *(const short8*)(Bb_ + (nt*16+l15)*72 + ks*32 + q*8);
    #pragma unroll
    for (int mt=0;mt<4;mt++)
      #pragma unroll
      for (int nt=0;nt<4;nt++)
        acc[mt][nt] = __builtin_amdgcn_mfma_f32_16x16x32_bf16(af[mt], bf4[nt], acc[mt][nt], 0,0,0);
  }
}

// ---------------- SSD pass 1: per chunk: Y_intra (masked attention form) + local state G ----
// grid (NCH, NHEADS, 2*BSZ), one wave per chunk
__global__ __launch_bounds__(64) void ssd1_k(const float* __restrict__ dAb,
    const unsigned short* __restrict__ dtxb, const unsigned short* __restrict__ Bb,
    const unsigned short* __restrict__ Cb,
    unsigned short* __restrict__ y0, unsigned short* __restrict__ y1,
    unsigned short* __restrict__ hbuf, float* __restrict__ Pch, float* __restrict__ ebuf){
  int ch = blockIdx.x, h = blockIdx.y, z = blockIdx.z;
  int d = z >> 1, b = z & 1;
  int lane = threadIdx.x;
  int l15 = lane & 15, q = lane >> 4;
  int tr = lane >> 3, cb8 = (lane & 7)*8;
  size_t tokb = (size_t)z*LSEQ + (size_t)ch*64;
  size_t zhc = ((size_t)z*NHEADS + h)*NCH + ch;
  __shared__ __align__(16) unsigned short S1[64*72];
  __shared__ __align__(16) unsigned short S2[64*72];
  __shared__ __align__(16) unsigned short S3[64*72];
  __shared__ float Lb[64];
  // cumulative log-decay (inclusive prefix over the wave)
  float L = fmaxf(logf(dAb[(tokb + lane)*NHEADS + h]), -60.f);
  #pragma unroll
  for (int off=1; off<64; off<<=1){
    float v = __shfl_up(L, off);
    if (lane >= off) L += v;
  }
  Lb[lane] = L;
  float e = expf(L);
  ebuf[zhc*64 + lane] = e;
  if (lane == 63) Pch[zhc] = e;
  // stage: S1=C [t][n], S2=B [t][n], S3=Xdt^T [p][s]
  for (int i=0;i<8;i++){
    int t = i*8 + tr;
    *(uint4*)&S1[t*72 + cb8] = *(const uint4*)(Cb + (tokb+t)*DSTATE + cb8);
    *(uint4*)&S2[t*72 + cb8] = *(const uint4*)(Bb + (tokb+t)*DSTATE + cb8);
    uint4 xv = *(const uint4*)(dtxb + (tokb+t)*DINNER + (size_t)h*64 + cb8);
    const unsigned short* xs = (const unsigned short*)&xv;
    #pragma unroll
    for (int j=0;j<8;j++) S3[(cb8+j)*72 + t] = xs[j];
  }
  // single wave: DS pipe is in-order, no barriers needed anywhere here
  // GEMM1: S[t][s] = C . B^T
  f32x4 sa[4][4];
  for (int i=0;i<4;i++) for (int j=0;j<4;j++) sa[i][j] = (f32x4){0.f,0.f,0.f,0.f};
  gemm64(S1, S2, l15, q, sa);
  // mask: P[t][s] = (t>=s) ? exp(L_t - L_s) * S : 0 ; write P into S1 (C dead)
  float Lsv[4];
  #pragma unroll
  for (int nt=0;nt<4;nt++) Lsv[nt] = Lb[nt*16 + l15];
  #pragma unroll
  for (int mt=0;mt<4;mt++){
    #pragma unroll
    for (int r=0;r<4;r++){
      int t = mt*16 + q*4 + r;
      float Lt = Lb[t];
      #pragma unroll
      for (int nt=0;nt<4;nt++){
        int s = nt*16 + l15;
        float v = (t >= s) ? expf(Lt - Lsv[nt]) * sa[mt][nt][r] : 0.f;
        S1[t*72 + s] = f2b(v);
      }
    }
  }
  // GEMM2: Y_intra[t][p] = P . Xdt  (A = P(S1), Bop = XdtT(S3))
  f32x4 ya[4][4];
  for (int i=0;i<4;i++) for (int j=0;j<4;j++) ya[i][j] = (f32x4){0.f,0.f,0.f,0.f};
  gemm64(S1, S3, l15, q, ya);
  // stage Y into S2 (B consumed), coalesced store to y (physical/flipped rows)
  #pragma unroll
  for (int mt=0;mt<4;mt++)
    #pragma unroll
    for (int pt=0;pt<4;pt++)
      #pragma unroll
      for (int r=0;r<4;r++)
        S2[(mt*16+q*4+r)*72 + pt*16 + l15] = f2b(ya[mt][pt][r]);
  unsigned short* yb = d ? y1 : y0;
  for (int i=0;i<8;i++){
    int t = i*8 + tr; int g = ch*64 + t;
    int tph = d ? (LSEQ-1-g) : g;
    *(uint4*)(yb + ((size_t)b*LSEQ + tph)*DINNER + (size_t)h*64 + cb8) = *(uint4*)&S2[t*72 + cb8];
  }
  // BwT[n][s] = exp(L63-L_s) * B[s][n]  into S2 (reload B from global/L2)
  float L63 = Lb[63];
  for (int i=0;i<8;i++){
    int s = i*8 + tr;
    float w = expf(L63 - Lb[s]);
    uint4 bv = *(const uint4*)(Bb + (tokb+s)*DSTATE + cb8);
    const unsigned short* bs = (const unsigned short*)&bv;
    #pragma unroll
    for (int j=0;j<8;j++) S2[(cb8+j)*72 + s] = f2b(w * b2f(bs[j]));
  }
  // GEMM3: G[p][n] = XdtT . Bw  (A = XdtT(S3), Bop = BwT(S2))
  f32x4 ga[4][4];
  for (int i=0;i<4;i++) for (int j=0;j<4;j++) ga[i][j] = (f32x4){0.f,0.f,0.f,0.f};
  gemm64(S3, S2, l15, q, ga);
  #pragma unroll
  for (int pt=0;pt<4;pt++)
    #pragma unroll
    for (int nt=0;nt<4;nt++)
      #pragma unroll
      for (int r=0;r<4;r++)
        S1[(pt*16+q*4+r)*72 + nt*16 + l15] = f2b(ga[pt][nt][r]);
  for (int i=0;i<8;i++){
    int p = i*8 + tr;
    *(uint4*)(hbuf + zhc*4096 + (size_t)p*64 + cb8) = *(uint4*)&S1[p*72 + cb8];
  }
}

// ---------------- combine chunk states, IN PLACE: hbuf[ch] := prefix state before ch ----
__global__ __launch_bounds__(256) void comb_k(unsigned short* __restrict__ hbuf,
    const float* __restrict__ Pch){
  int u = blockIdx.x; int tid = threadIdx.x;
  float hreg[16];
  #pragma unroll
  for (int k=0;k<16;k++) hreg[k]=0.f;
  for (int ch=0; ch<NCH; ch++){
    size_t base = ((size_t)u*NCH + ch)*4096;
    float P = Pch[(size_t)u*NCH + ch];
    #pragma unroll
    for (int k=0;k<16;k++){
      float t = b2f(hbuf[base + tid + k*256]);
      hbuf[base + tid + k*256] = f2b(hreg[k]);
      hreg[k] = hreg[k]*P + t;
    }
  }
}

// ---------------- SSD pass 2: Y += diag(e) C h_in^T + D*xh ----------------
__global__ __launch_bounds__(64) void ssd2_k(const unsigned short* __restrict__ Cb,
    const unsigned short* __restrict__ hbuf, const unsigned short* __restrict__ dtxb,
    const float* __restrict__ dtb, const float* __restrict__ ebuf, const float* __restrict__ Dh,
    unsigned short* __restrict__ y0, unsigned short* __restrict__ y1){
  int ch = blockIdx.x, h = blockIdx.y, z = blockIdx.z;
  int d = z >> 1, b = z & 1;
  int lane = threadIdx.x;
  int l15 = lane & 15, q = lane >> 4;
  int tr = lane >> 3, cb8 = (lane & 7)*8;
  size_t tokb = (size_t)z*LSEQ + (size_t)ch*64;
  size_t zhc = ((size_t)z*NHEADS + h)*NCH + ch;
  __shared__ __align__(16) unsigned short S1[64*72];
  __shared__ __align__(16) unsigned short S2[64*72];
  __shared__ __align__(16) unsigned short S3[64*72];
  __shared__ float eb2[64], dti[64];
  eb2[lane] = ebuf[zhc*64 + lane];
  dti[lane] = 1.f / dtb[(tokb + lane)*NHEADS + h];
  float Dv = Dh[h];
  for (int i=0;i<8;i++){
    int t = i*8 + tr;
    *(uint4*)&S1[t*72 + cb8] = *(const uint4*)(Cb + (tokb+t)*DSTATE + cb8);
    *(uint4*)&S2[t*72 + cb8] = *(const uint4*)(hbuf + zhc*4096 + (size_t)t*64 + cb8); // rows p
  }
  f32x4 acc[4][4];
  for (int i=0;i<4;i++) for (int j=0;j<4;j++) acc[i][j] = (f32x4){0.f,0.f,0.f,0.f};
  gemm64(S1, S2, l15, q, acc);   // acc[t][p] = C . h_in^T
  unsigned short* yb = d ? y1 : y0;
  #pragma unroll
  for (int mt=0;mt<4;mt++){
    #pragma unroll
    for (int r=0;r<4;r++){
      int t = mt*16 + q*4 + r; int g = ch*64 + t;
      int tph = d ? (LSEQ-1-g) : g;
      size_t rowb = ((size_t)b*LSEQ + tph)*DINNER + (size_t)h*64;
      size_t dxb_ = (tokb + t)*DINNER + (size_t)h*64;
      float et = eb2[t], di = dti[t];
      #pragma unroll
      for (int pt=0;pt<4;pt++){
        int p = pt*16 + l15;
        float v = acc[mt][pt][r]*et + b2f(yb[rowb + p]) + Dv * b2f(dtxb[dxb_ + p]) * di;
        S3[t*72 + p] = f2b(v);
      }
    }
  }
  for (int i=0;i<8;i++){
    int t = i*8 + tr; int g = ch*64 + t;
    int tph = d ? (LSEQ-1-g) : g;
    *(uint4*)(yb + ((size_t)b*LSEQ + tph)*DINNER + (size_t)h*64 + cb8) = *(uint4*)&S3[t*72 + cb8];
  }
}

// ---------------- gate: g=y*silu(z), per-dir rmsnorm, sum, ->bf16 ----------------
__global__ __launch_bounds__(256) void gate_k(const unsigned short* __restrict__ y0,
    const unsigned short* __restrict__ y1, const unsigned short* __restrict__ zcomp,
    const float* __restrict__ mnw, unsigned short* __restrict__ gsum){
  int tok = blockIdx.x; int tid = threadIdx.x;
  __shared__ float g0s[DINNER], g1s[DINNER];
  float ss0 = 0.f, ss1 = 0.f;
  for (int i=0;i<4;i++){
    int c = tid + i*256;
    float z = b2f(zcomp[(size_t)tok*DINNER + c]);
    float sz = z / (1.f + expf(-z));
    float g0 = b2f(y0[(size_t)tok*DINNER + c]) * sz;
    float g1 = b2f(y1[(size_t)tok*DINNER + c]) * sz;
    g0s[c] = g0; g1s[c] = g1;
    ss0 += g0*g0; ss1 += g1*g1;
  }
  for (int m=32;m>=1;m>>=1){ ss0 += __shfl_xor(ss0,m); ss1 += __shfl_xor(ss1,m); }
  __shared__ float w0[4], w1[4];
  int wave = tid>>6, lane = tid&63;
  if (lane==0){ w0[wave]=ss0; w1[wave]=ss1; }
  __syncthreads();
  ss0 = w0[0]+w0[1]+w0[2]+w0[3];
  ss1 = w1[0]+w1[1]+w1[2]+w1[3];
  float r0 = rsqrtf(ss0*(1.f/DINNER) + 1e-5f);
  float r1 = rsqrtf(ss1*(1.f/DINNER) + 1e-5f);
  for (int i=0;i<4;i++){
    int c = tid + i*256;
    gsum[(size_t)tok*DINNER + c] = f2b((g0s[c]*r0 + g1s[c]*r1) * mnw[c]);
  }
}

extern "C" void kernel_launch(void* const* d_in, const int* in_sizes, int n_in,
                              void* d_out, int out_size, void* d_ws, size_t ws_size,
                              hipStream_t stream){
  const float* x       = (const float*)d_in[0];
  const float* nin_w   = (const float*)d_in[1];
  const float* nin_b   = (const float*)d_in[2];
  const float* nout_w  = (const float*)d_in[3];
  const float* nout_b  = (const float*)d_in[4];
  const float* in_w    = (const float*)d_in[5];
  const float* conv_w  = (const float*)d_in[6];
  const float* conv_b  = (const float*)d_in[7];
  const float* dt_bias = (const float*)d_in[8];
  const float* A_log   = (const float*)d_in[9];
  const float* D_h     = (const float*)d_in[10];
  const float* mnorm_w = (const float*)d_in[11];
  const float* out_w   = (const float*)d_in[12];
  const float* ff_w1   = (const float*)d_in[13];
  const float* ff_b1   = (const float*)d_in[14];
  const float* ff_w2   = (const float*)d_in[15];
  const float* ff_b2   = (const float*)d_in[16];
  float* out = (float*)d_out;

  char* ws = (char*)d_ws;
  size_t off = 0;
  auto alloc = [&](size_t bytes)->char*{
    char* p = ws + off; off = (off + bytes + 255) & ~(size_t)255; return p; };
  unsigned short* xn_bf = (unsigned short*)alloc((size_t)NTOK*DMODEL*2);
  unsigned short* in_wT = (unsigned short*)alloc((size_t)NPAD*DMODEL*2);
  unsigned short* out_wT= (unsigned short*)alloc((size_t)DMODEL*DINNER*2);
  unsigned short* w1T   = (unsigned short*)alloc((size_t)2048*DMODEL*2);
  unsigned short* w2T   = (unsigned short*)alloc((size_t)DMODEL*2048*2);
  unsigned short* zx    = (unsigned short*)alloc((size_t)NTOK*NPAD*2);      // 37.7 MB
  unsigned short* zcomp = (unsigned short*)alloc((size_t)NTOK*DINNER*2);    // 16.8 MB
  float*          dAb   = (float*)alloc((size_t)2*NTOK*NHEADS*4);
  float*          dtb   = (float*)alloc((size_t)2*NTOK*NHEADS*4);
  unsigned short* Bb    = (unsigned short*)alloc((size_t)2*NTOK*DSTATE*2);
  unsigned short* Cb    = (unsigned short*)alloc((size_t)2*NTOK*DSTATE*2);
  unsigned short* dtxb  = (unsigned short*)alloc((size_t)2*NTOK*DINNER*2);  // 33.6 MB
  unsigned short* y0    = (unsigned short*)alloc((size_t)NTOK*DINNER*2);    // 16.8 MB
  unsigned short* y1    = (unsigned short*)alloc((size_t)NTOK*DINNER*2);    // 16.8 MB
  float*          Pch   = (float*)alloc((size_t)64*NCH*4);
  float*          ebuf  = (float*)alloc((size_t)64*NCH*64*4);               // 1.05 MB
  size_t need = off;
  if (need > ws_size) return;  // fail absmax cleanly instead of faulting

  // aliases into sequentially-dead regions:
  unsigned short* hbuf  = zx;                          // 33.5MB chunk states; zx dead after prep_k
  unsigned short* gsum  = dtxb;                        // dtxb dead after ssd2_k
  float* mpre = (float*)(dtxb + (size_t)NTOK*DINNER);  // 2nd half of dtxb
  unsigned short* m_bf  = y0;                          // y0 dead after gate_k
  unsigned short* h1    = zx;                          // hbuf dead after ssd2_k

  // weight transposes -> bf16 [N][K]
  wconv_t<<<dim3(NPAD/32,   DMODEL/32), 256, 0, stream>>>(in_w,  in_wT,  DMODEL, DPROJ,  NPAD);
  wconv_t<<<dim3(DMODEL/32, DINNER/32), 256, 0, stream>>>(out_w, out_wT, DINNER, DMODEL, DMODEL);
  wconv_t<<<dim3(2048/32,   DMODEL/32), 256, 0, stream>>>(ff_w1, w1T,    DMODEL, 2048,   2048);
  wconv_t<<<dim3(DMODEL/32, 2048/32),   256, 0, stream>>>(ff_w2, w2T,    2048,   DMODEL, DMODEL);
  // LN in -> bf16
  layernorm_k<<<NTOK, 256, 0, stream>>>(x, nin_w, nin_b, xn_bf);
  // in_proj (shared between directions) -> bf16 zx
  gemm_k<<<dim3(NPAD/128, NTOK/128), 256, 0, stream>>>(xn_bf, in_wT, zx, NTOK, NPAD, DMODEL, 3, nullptr, nullptr);
  // conv/silu/dt prep for both directions (+ z compaction)
  prep_k<<<2*NTOK, 256, 0, stream>>>(zx, conv_w, conv_b, dt_bias, A_log, dAb, dtb, dtxb, Bb, Cb, zcomp);
  // chunked SSD: intra-chunk (MFMA) -> combine -> inter-chunk (MFMA)
  ssd1_k<<<dim3(NCH, NHEADS, 2*BSZ), 64, 0, stream>>>(dAb, dtxb, Bb, Cb, y0, y1, hbuf, Pch, ebuf);
  comb_k<<<64, 256, 0, stream>>>(hbuf, Pch);
  ssd2_k<<<dim3(NCH, NHEADS, 2*BSZ), 64, 0, stream>>>(Cb, hbuf, dtxb, dtb, ebuf, D_h, y0, y1);
  // gate + per-dir rmsnorm + sum (linearity: single out_proj GEMM)
  gate_k<<<NTOK, 256, 0, stream>>>(y0, y1, zcomp, mnorm_w, gsum);
  // out_proj -> f32 mpre
  gemm_k<<<dim3(DMODEL/128, NTOK/128), 256, 0, stream>>>(gsum, out_wT, mpre, NTOK, DMODEL, DINNER, 0, nullptr, nullptr);
  // LN out -> bf16
  layernorm_k<<<NTOK, 256, 0, stream>>>(mpre, nout_w, nout_b, m_bf);
  // ff1 + gelu -> bf16
  gemm_k<<<dim3(2048/128, NTOK/128), 256, 0, stream>>>(m_bf, w1T, h1, NTOK, 2048, DMODEL, 1, ff_b1, nullptr);
  // ff2 + bias + residual -> f32 out
  gemm_k<<<dim3(DMODEL/128, NTOK/128), 256, 0, stream>>>(h1, w2T, out, NTOK, DMODEL, 2048, 2, ff_b2, x);
}

// Round 7
// 461.469 us; speedup vs baseline: 4.0279x; 1.0659x over previous
//
#include <hip/hip_runtime.h>
#include <hip/hip_bf16.h>

#define LSEQ 4096
#define BSZ 2
#define DMODEL 512
#define DINNER 1024
#define DSTATE 64
#define NHEADS 16
#define CONVDIM 1152
#define DPROJ 2192
#define NPAD 2304
#define NTOK (BSZ*LSEQ)
#define NCH 64   /* 64-token chunks */

typedef __attribute__((ext_vector_type(8))) short short8;
typedef __attribute__((ext_vector_type(4))) float f32x4;

__device__ inline unsigned short f2b(float v){
  unsigned int u = __builtin_bit_cast(unsigned int, v);
  unsigned int r = (u + 0x7FFFu + ((u >> 16) & 1u)) >> 16;
  return (unsigned short)r;
}
__device__ inline float b2f(unsigned short u){
  unsigned int x = ((unsigned int)u) << 16;
  return __builtin_bit_cast(float, x);
}
__device__ inline uint4 pack8(const float* v){
  uint4 pk;
  pk.x = (unsigned)f2b(v[0]) | ((unsigned)f2b(v[1])<<16);
  pk.y = (unsigned)f2b(v[2]) | ((unsigned)f2b(v[3])<<16);
  pk.z = (unsigned)f2b(v[4]) | ((unsigned)f2b(v[5])<<16);
  pk.w = (unsigned)f2b(v[6]) | ((unsigned)f2b(v[7])<<16);
  return pk;
}

// ---------------- weight transpose + f32->bf16 (src [K][Nsrc] -> dst [Npad][K]) ----
__global__ __launch_bounds__(256) void wconv_t(const float* __restrict__ src,
    unsigned short* __restrict__ dst, int K, int Nsrc, int Npad){
  __shared__ float t[32][33];
  int n0 = blockIdx.x*32, k0 = blockIdx.y*32;
  int tx = threadIdx.x & 31, ty = threadIdx.x >> 5;
  for (int i=0;i<4;i++){
    int k = k0 + ty + i*8; int n = n0 + tx;
    t[ty + i*8][tx] = (n < Nsrc) ? src[(size_t)k*Nsrc + n] : 0.f;
  }
  __syncthreads();
  for (int i=0;i<4;i++){
    int n = n0 + ty + i*8; int k = k0 + tx;
    if (n < Npad) dst[(size_t)n*K + k] = f2b(t[tx][ty + i*8]);
  }
}

// ---------------- layernorm over 512 cols (f32 in) -> bf16 ----------------
__global__ __launch_bounds__(256) void layernorm_k(const float* __restrict__ in,
    const float* __restrict__ w, const float* __restrict__ bb, unsigned short* __restrict__ out){
  int row = blockIdx.x; int tid = threadIdx.x;
  const float* r = in + (size_t)row*DMODEL;
  float v0 = r[tid], v1 = r[tid+256];
  float s = v0+v1, sq = v0*v0+v1*v1;
  for (int m=32;m>=1;m>>=1){ s += __shfl_xor(s,m); sq += __shfl_xor(sq,m); }
  __shared__ float ws_[4], wq_[4];
  int wave = tid>>6, lane = tid&63;
  if (lane==0){ ws_[wave]=s; wq_[wave]=sq; }
  __syncthreads();
  s = ws_[0]+ws_[1]+ws_[2]+ws_[3]; sq = wq_[0]+wq_[1]+wq_[2]+wq_[3];
  float mu = s * (1.f/DMODEL);
  float var = sq * (1.f/DMODEL) - mu*mu;
  float rs = rsqrtf(var + 1e-5f);
  out[(size_t)row*DMODEL + tid]     = f2b((v0-mu)*rs*w[tid] + bb[tid]);
  out[(size_t)row*DMODEL + tid+256] = f2b((v1-mu)*rs*w[tid+256] + bb[tid+256]);
}

// ---------------- bf16 MFMA GEMM: C[M,N] = A[M,K] @ Bt[N,K]^T ----------------
// epi 0: f32 plain ; 1: bf16 gelu(v+bias) ; 2: f32 v+bias+resid ; 3: bf16 plain
__global__ __launch_bounds__(256) void gemm_k(const unsigned short* __restrict__ A,
    const unsigned short* __restrict__ Bt, void* __restrict__ outp,
    int M, int N, int K, int epi, const float* __restrict__ bias, const float* __restrict__ resid){
  __shared__ __align__(16) unsigned short smem[2*128*40];
  unsigned short* As = smem;
  unsigned short* Bs = smem + 128*40;
  int tid = threadIdx.x;
  int lane = tid & 63, wave = tid >> 6;
  int wr = wave >> 1, wc = wave & 1;
  int l15 = lane & 15, q = lane >> 4;
  int bm = blockIdx.y, bn = blockIdx.x;
  f32x4 acc[4][4];
  for (int i=0;i<4;i++) for(int j=0;j<4;j++) acc[i][j] = (f32x4){0.f,0.f,0.f,0.f};
  const size_t abase = (size_t)bm*128*K;
  const size_t bbase = (size_t)bn*128*K;
  for (int k0 = 0; k0 < K; k0 += 32){
    for (int i=0;i<2;i++){
      int idx = tid + i*256; int rr = idx>>2, cg = idx&3;
      *(uint4*)(&As[rr*40 + cg*8]) = *(const uint4*)(A + abase + (size_t)rr*K + k0 + cg*8);
      *(uint4*)(&Bs[rr*40 + cg*8]) = *(const uint4*)(Bt + bbase + (size_t)rr*K + k0 + cg*8);
    }
    __syncthreads();
    short8 af[4], bfr[4];
    for (int mt=0;mt<4;mt++) af[mt]  = *(const short8*)(&As[(wr*64+mt*16+l15)*40 + q*8]);
    for (int nt=0;nt<4;nt++) bfr[nt] = *(const short8*)(&Bs[(wc*64+nt*16+l15)*40 + q*8]);
    for (int mt=0;mt<4;mt++)
      for (int nt=0;nt<4;nt++)
        acc[mt][nt] = __builtin_amdgcn_mfma_f32_16x16x32_bf16(af[mt], bfr[nt], acc[mt][nt], 0,0,0);
    __syncthreads();
  }
  // ---- coalesced epilogue (per-wave 16x65-f32 LDS slab) ----
  float* cbuf = ((float*)smem) + wave*1040;
  int rbase = q*4;
  int gr0t = bm*128 + wr*64;
  int gc0 = bn*128 + wc*64;
  for (int mt=0; mt<4; mt++){
    for (int nt=0;nt<4;nt++)
      for (int rr=0;rr<4;rr++)
        cbuf[(rbase+rr)*65 + nt*16 + l15] = acc[mt][nt][rr];
    int gr0 = gr0t + mt*16;
    if (epi == 1 || epi == 3){
      int r8 = lane >> 3, c0 = (lane & 7)*8;
      #pragma unroll
      for (int h=0; h<2; h++){
        int row = h*8 + r8;
        float v[8];
        #pragma unroll
        for (int t=0;t<8;t++) v[t] = cbuf[row*65 + c0 + t];
        if (epi == 1){
          #pragma unroll
          for (int t=0;t<8;t++){
            float bv = v[t] + bias[gc0 + c0 + t];
            v[t] = 0.5f*bv*(1.f+erff(bv*0.70710678118654752f));
          }
        }
        *(uint4*)((unsigned short*)outp + (size_t)(gr0+row)*N + gc0 + c0) = pack8(v);
      }
    } else {
      int r4 = lane >> 4, c0 = (lane & 15)*4;
      #pragma unroll
      for (int h=0; h<4; h++){
        int row = h*4 + r4;
        float4 v;
        v.x = cbuf[row*65 + c0 + 0];
        v.y = cbuf[row*65 + c0 + 1];
        v.z = cbuf[row*65 + c0 + 2];
        v.w = cbuf[row*65 + c0 + 3];
        if (epi == 2){
          const float4 rv = *(const float4*)(resid + (size_t)(gr0+row)*N + gc0 + c0);
          v.x += bias[gc0+c0+0] + rv.x;
          v.y += bias[gc0+c0+1] + rv.y;
          v.z += bias[gc0+c0+2] + rv.z;
          v.w += bias[gc0+c0+3] + rv.w;
        }
        *(float4*)((float*)outp + (size_t)(gr0+row)*N + gc0 + c0) = v;
      }
    }
  }
}

// ---------------- dt/dA per (token, head), written for both directions ----------------
__global__ __launch_bounds__(256) void dt_k(const unsigned short* __restrict__ zx,
    const float* __restrict__ dt_bias, const float* __restrict__ A_log,
    float* __restrict__ dAb, float* __restrict__ dtb){
  int b = blockIdx.y;
  int t = blockIdx.x*16 + (threadIdx.x>>4);
  int h = threadIdx.x & 15;
  float raw = b2f(zx[((size_t)b*LSEQ + t)*NPAD + (DINNER+CONVDIM) + h]) + dt_bias[h];
  float dt = (raw > 20.f) ? raw : log1pf(expf(raw));
  float dA = expf(-expf(A_log[h]) * dt);
  size_t f = ((size_t)b*LSEQ + t)*NHEADS + h;
  size_t r = ((size_t)(BSZ+b)*LSEQ + (LSEQ-1-t))*NHEADS + h;
  dAb[f] = dA; dtb[f] = dt;
  dAb[r] = dA; dtb[r] = dt;
}

// ---------------- conv+silu for x-channels, BOTH directions, + z compaction ----------
// thread = 8-channel group (uint4); sliding 4-deep window over a 16-token sub-tile.
// fwd[t] = sum_k w[k]*x[t-3+k]; bwd at physical tau: sum_k w[k]*x[tau+3-k] (same window).
__global__ __launch_bounds__(256) void conv_x_k(const unsigned short* __restrict__ zx,
    const float* __restrict__ conv_w, const float* __restrict__ conv_b,
    const float* __restrict__ dtb, unsigned short* __restrict__ dtxb,
    unsigned short* __restrict__ zcomp){
  int b = blockIdx.y;
  int t0blk = blockIdx.x * 32;
  int tid = threadIdx.x;
  int half = tid >> 7, cg = tid & 127;
  int c0 = cg * 8;
  int head = c0 >> 6;
  float wk[4][8], bias8[8];
  #pragma unroll
  for (int k=0;k<4;k++)
    #pragma unroll
    for (int j=0;j<8;j++) wk[k][j] = conv_w[k*CONVDIM + c0 + j];
  #pragma unroll
  for (int j=0;j<8;j++) bias8[j] = conv_b[c0 + j];
  __shared__ float sdtf[32][16], sdtb[32][16];
  for (int r = tid; r < 512; r += 256){
    int i = r >> 4, h = r & 15;
    sdtf[i][h] = dtb[((size_t)b*LSEQ + t0blk + i)*NHEADS + h];
    sdtb[i][h] = dtb[((size_t)(BSZ+b)*LSEQ + (LSEQ-1-(t0blk+i)))*NHEADS + h];
  }
  __syncthreads();
  int t0 = t0blk + half*16;
  float w0[8],w1[8],w2[8],w3[8];
  #pragma unroll
  for (int j=0;j<8;j++){ w1[j]=0.f; w2[j]=0.f; w3[j]=0.f; }
  for (int it=0; it<22; ++it){
    int t = t0 - 3 + it;
    #pragma unroll
    for (int j=0;j<8;j++){ w0[j]=w1[j]; w1[j]=w2[j]; w2[j]=w3[j]; }
    if (t >= 0 && t < LSEQ){
      uint4 xv = *(const uint4*)(zx + ((size_t)b*LSEQ + t)*NPAD + DINNER + c0);
      const unsigned short* xs = (const unsigned short*)&xv;
      #pragma unroll
      for (int j=0;j<8;j++) w3[j] = b2f(xs[j]);
      if (t >= t0 && t < t0+16){
        uint4 zv = *(const uint4*)(zx + ((size_t)b*LSEQ + t)*NPAD + c0);
        *(uint4*)(zcomp + ((size_t)b*LSEQ + t)*DINNER + c0) = zv;
      }
    } else {
      #pragma unroll
      for (int j=0;j<8;j++) w3[j] = 0.f;
    }
    if (t >= t0 && t < t0+16){
      float dtf = sdtf[t - t0blk][head];
      float v[8];
      #pragma unroll
      for (int j=0;j<8;j++){
        float a = bias8[j] + wk[0][j]*w0[j] + wk[1][j]*w1[j] + wk[2][j]*w2[j] + wk[3][j]*w3[j];
        v[j] = (a / (1.f + expf(-a))) * dtf;
      }
      *(uint4*)(dtxb + ((size_t)b*LSEQ + t)*DINNER + c0) = pack8(v);
    }
    int tau = t - 3;
    if (tau >= t0 && tau < t0+16){
      float dtv = sdtb[tau - t0blk][head];
      float v[8];
      #pragma unroll
      for (int j=0;j<8;j++){
        float a = bias8[j] + wk[0][j]*w3[j] + wk[1][j]*w2[j] + wk[2][j]*w1[j] + wk[3][j]*w0[j];
        v[j] = (a / (1.f + expf(-a))) * dtv;
      }
      *(uint4*)(dtxb + ((size_t)(BSZ+b)*LSEQ + (LSEQ-1-tau))*DINNER + c0) = pack8(v);
    }
  }
}

// ---------------- conv+silu for B/C channels, both directions ----------------
// block: 16 slots x 16 c-groups; slot = 4-token sub-tile with sliding window
__global__ __launch_bounds__(256) void conv_bc_k(const unsigned short* __restrict__ zx,
    const float* __restrict__ conv_w, const float* __restrict__ conv_b,
    unsigned short* __restrict__ Bb, unsigned short* __restrict__ Cb){
  int b = blockIdx.y;
  int t0blk = blockIdx.x * 64;
  int tid = threadIdx.x;
  int slot = tid >> 4, cg = tid & 15;
  int c0 = cg*8;                 // 0..127 within BC region
  int ccol = DINNER + 1024 + c0; // zx column
  int cw = 1024 + c0;            // conv_w column
  float wk[4][8], bias8[8];
  #pragma unroll
  for (int k=0;k<4;k++)
    #pragma unroll
    for (int j=0;j<8;j++) wk[k][j] = conv_w[k*CONVDIM + cw + j];
  #pragma unroll
  for (int j=0;j<8;j++) bias8[j] = conv_b[cw + j];
  int t0 = t0blk + slot*4;
  float w0[8],w1[8],w2[8],w3[8];
  #pragma unroll
  for (int j=0;j<8;j++){ w1[j]=0.f; w2[j]=0.f; w3[j]=0.f; }
  for (int it=0; it<10; ++it){
    int t = t0 - 3 + it;
    #pragma unroll
    for (int j=0;j<8;j++){ w0[j]=w1[j]; w1[j]=w2[j]; w2[j]=w3[j]; }
    if (t >= 0 && t < LSEQ){
      uint4 xv = *(const uint4*)(zx + ((size_t)b*LSEQ + t)*NPAD + ccol);
      const unsigned short* xs = (const unsigned short*)&xv;
      #pragma unroll
      for (int j=0;j<8;j++) w3[j] = b2f(xs[j]);
    } else {
      #pragma unroll
      for (int j=0;j<8;j++) w3[j] = 0.f;
    }
    if (t >= t0 && t < t0+4){
      float v[8];
      #pragma unroll
      for (int j=0;j<8;j++){
        float a = bias8[j] + wk[0][j]*w0[j] + wk[1][j]*w1[j] + wk[2][j]*w2[j] + wk[3][j]*w3[j];
        v[j] = a / (1.f + expf(-a));
      }
      size_t tok = (size_t)b*LSEQ + t;
      if (c0 < 64) *(uint4*)(Bb + tok*DSTATE + c0)      = pack8(v);
      else         *(uint4*)(Cb + tok*DSTATE + (c0-64)) = pack8(v);
    }
    int tau = t - 3;
    if (tau >= t0 && tau < t0+4){
      float v[8];
      #pragma unroll
      for (int j=0;j<8;j++){
        float a = bias8[j] + wk[0][j]*w3[j] + wk[1][j]*w2[j] + wk[2][j]*w1[j] + wk[3][j]*w0[j];
        v[j] = a / (1.f + expf(-a));
      }
      size_t tok = (size_t)(BSZ+b)*LSEQ + (LSEQ-1-tau);
      if (c0 < 64) *(uint4*)(Bb + tok*DSTATE + c0)      = pack8(v);
      else         *(uint4*)(Cb + tok*DSTATE + (c0-64)) = pack8(v);
    }
  }
}

// ---- 64x64x64 bf16 GEMM on one wave: D += A(S-rows m, k contiguous) * B(S-rows n)^T
__device__ inline void gemm64(const unsigned short* Ab, const unsigned short* Bb_,
                              int l15, int q, f32x4 acc[4][4]){
  #pragma unroll
  for (int ks=0; ks<2; ks++){
    short8 af[4], bf4[4];
    #pragma unroll
    for (int mt=0;mt<4;mt++) af[mt]  = *(const short8*)(Ab  + (mt*16+l15)*72 + ks*32 + q*8);
    #pragma unroll
    for (int nt=0;nt<4;nt++) bf4[nt] = *(const short8*)(Bb_ + (nt*16+l15)*72 + ks*32 + q*8);
    #pragma unroll
    for (int mt=0;mt<4;mt++)
      #pragma unroll
      for (int nt=0;nt<4;nt++)
        acc[mt][nt] = __builtin_amdgcn_mfma_f32_16x16x32_bf16(af[mt], bf4[nt], acc[mt][nt], 0,0,0);
  }
}

// ---------------- SSD pass 1: per chunk: Y_intra (masked attention form) + local state G ----
__global__ __launch_bounds__(64) void ssd1_k(const float* __restrict__ dAb,
    const unsigned short* __restrict__ dtxb, const unsigned short* __restrict__ Bb,
    const unsigned short* __restrict__ Cb,
    unsigned short* __restrict__ y0, unsigned short* __restrict__ y1,
    unsigned short* __restrict__ hbuf, float* __restrict__ Pch, float* __restrict__ ebuf){
  int ch = blockIdx.x, h = blockIdx.y, z = blockIdx.z;
  int d = z >> 1, b = z & 1;
  int lane = threadIdx.x;
  int l15 = lane & 15, q = lane >> 4;
  int tr = lane >> 3, cb8 = (lane & 7)*8;
  size_t tokb = (size_t)z*LSEQ + (size_t)ch*64;
  size_t zhc = ((size_t)z*NHEADS + h)*NCH + ch;
  __shared__ __align__(16) unsigned short S1[64*72];
  __shared__ __align__(16) unsigned short S2[64*72];
  __shared__ __align__(16) unsigned short S3[64*72];
  __shared__ float Lb[64];
  float L = fmaxf(logf(dAb[(tokb + lane)*NHEADS + h]), -60.f);
  #pragma unroll
  for (int off=1; off<64; off<<=1){
    float v = __shfl_up(L, off);
    if (lane >= off) L += v;
  }
  Lb[lane] = L;
  float e = expf(L);
  ebuf[zhc*64 + lane] = e;
  if (lane == 63) Pch[zhc] = e;
  for (int i=0;i<8;i++){
    int t = i*8 + tr;
    *(uint4*)&S1[t*72 + cb8] = *(const uint4*)(Cb + (tokb+t)*DSTATE + cb8);
    *(uint4*)&S2[t*72 + cb8] = *(const uint4*)(Bb + (tokb+t)*DSTATE + cb8);
    uint4 xv = *(const uint4*)(dtxb + (tokb+t)*DINNER + (size_t)h*64 + cb8);
    const unsigned short* xs = (const unsigned short*)&xv;
    #pragma unroll
    for (int j=0;j<8;j++) S3[(cb8+j)*72 + t] = xs[j];
  }
  f32x4 sa[4][4];
  for (int i=0;i<4;i++) for (int j=0;j<4;j++) sa[i][j] = (f32x4){0.f,0.f,0.f,0.f};
  gemm64(S1, S2, l15, q, sa);
  float Lsv[4];
  #pragma unroll
  for (int nt=0;nt<4;nt++) Lsv[nt] = Lb[nt*16 + l15];
  #pragma unroll
  for (int mt=0;mt<4;mt++){
    #pragma unroll
    for (int r=0;r<4;r++){
      int t = mt*16 + q*4 + r;
      float Lt = Lb[t];
      #pragma unroll
      for (int nt=0;nt<4;nt++){
        int s = nt*16 + l15;
        float v = (t >= s) ? expf(Lt - Lsv[nt]) * sa[mt][nt][r] : 0.f;
        S1[t*72 + s] = f2b(v);
      }
    }
  }
  f32x4 ya[4][4];
  for (int i=0;i<4;i++) for (int j=0;j<4;j++) ya[i][j] = (f32x4){0.f,0.f,0.f,0.f};
  gemm64(S1, S3, l15, q, ya);
  #pragma unroll
  for (int mt=0;mt<4;mt++)
    #pragma unroll
    for (int pt=0;pt<4;pt++)
      #pragma unroll
      for (int r=0;r<4;r++)
        S2[(mt*16+q*4+r)*72 + pt*16 + l15] = f2b(ya[mt][pt][r]);
  unsigned short* yb = d ? y1 : y0;
  for (int i=0;i<8;i++){
    int t = i*8 + tr; int g = ch*64 + t;
    int tph = d ? (LSEQ-1-g) : g;
    *(uint4*)(yb + ((size_t)b*LSEQ + tph)*DINNER + (size_t)h*64 + cb8) = *(uint4*)&S2[t*72 + cb8];
  }
  float L63 = Lb[63];
  for (int i=0;i<8;i++){
    int s = i*8 + tr;
    float w = expf(L63 - Lb[s]);
    uint4 bv = *(const uint4*)(Bb + (tokb+s)*DSTATE + cb8);
    const unsigned short* bs = (const unsigned short*)&bv;
    #pragma unroll
    for (int j=0;j<8;j++) S2[(cb8+j)*72 + s] = f2b(w * b2f(bs[j]));
  }
  f32x4 ga[4][4];
  for (int i=0;i<4;i++) for (int j=0;j<4;j++) ga[i][j] = (f32x4){0.f,0.f,0.f,0.f};
  gemm64(S3, S2, l15, q, ga);
  #pragma unroll
  for (int pt=0;pt<4;pt++)
    #pragma unroll
    for (int nt=0;nt<4;nt++)
      #pragma unroll
      for (int r=0;r<4;r++)
        S1[(pt*16+q*4+r)*72 + nt*16 + l15] = f2b(ga[pt][nt][r]);
  for (int i=0;i<8;i++){
    int p = i*8 + tr;
    *(uint4*)(hbuf + zhc*4096 + (size_t)p*64 + cb8) = *(uint4*)&S1[p*72 + cb8];
  }
}

// ---------------- combine chunk states, IN PLACE ----------------
__global__ __launch_bounds__(256) void comb_k(unsigned short* __restrict__ hbuf,
    const float* __restrict__ Pch){
  int u = blockIdx.x; int tid = threadIdx.x;
  float hreg[16];
  #pragma unroll
  for (int k=0;k<16;k++) hreg[k]=0.f;
  for (int ch=0; ch<NCH; ch++){
    size_t base = ((size_t)u*NCH + ch)*4096;
    float P = Pch[(size_t)u*NCH + ch];
    #pragma unroll
    for (int k=0;k<16;k++){
      float t = b2f(hbuf[base + tid + k*256]);
      hbuf[base + tid + k*256] = f2b(hreg[k]);
      hreg[k] = hreg[k]*P + t;
    }
  }
}

// ---------------- SSD pass 2: Y += diag(e) C h_in^T + D*xh ----------------
__global__ __launch_bounds__(64) void ssd2_k(const unsigned short* __restrict__ Cb,
    const unsigned short* __restrict__ hbuf, const unsigned short* __restrict__ dtxb,
    const float* __restrict__ dtb, const float* __restrict__ ebuf, const float* __restrict__ Dh,
    unsigned short* __restrict__ y0, unsigned short* __restrict__ y1){
  int ch = blockIdx.x, h = blockIdx.y, z = blockIdx.z;
  int d = z >> 1, b = z & 1;
  int lane = threadIdx.x;
  int l15 = lane & 15, q = lane >> 4;
  int tr = lane >> 3, cb8 = (lane & 7)*8;
  size_t tokb = (size_t)z*LSEQ + (size_t)ch*64;
  size_t zhc = ((size_t)z*NHEADS + h)*NCH + ch;
  __shared__ __align__(16) unsigned short S1[64*72];
  __shared__ __align__(16) unsigned short S2[64*72];
  __shared__ __align__(16) unsigned short S3[64*72];
  __shared__ float eb2[64], dti[64];
  eb2[lane] = ebuf[zhc*64 + lane];
  dti[lane] = 1.f / dtb[(tokb + lane)*NHEADS + h];
  float Dv = Dh[h];
  for (int i=0;i<8;i++){
    int t = i*8 + tr;
    *(uint4*)&S1[t*72 + cb8] = *(const uint4*)(Cb + (tokb+t)*DSTATE + cb8);
    *(uint4*)&S2[t*72 + cb8] = *(const uint4*)(hbuf + zhc*4096 + (size_t)t*64 + cb8);
  }
  f32x4 acc[4][4];
  for (int i=0;i<4;i++) for (int j=0;j<4;j++) acc[i][j] = (f32x4){0.f,0.f,0.f,0.f};
  gemm64(S1, S2, l15, q, acc);
  unsigned short* yb = d ? y1 : y0;
  #pragma unroll
  for (int mt=0;mt<4;mt++){
    #pragma unroll
    for (int r=0;r<4;r++){
      int t = mt*16 + q*4 + r; int g = ch*64 + t;
      int tph = d ? (LSEQ-1-g) : g;
      size_t rowb = ((size_t)b*LSEQ + tph)*DINNER + (size_t)h*64;
      size_t dxb_ = (tokb + t)*DINNER + (size_t)h*64;
      float et = eb2[t], di = dti[t];
      #pragma unroll
      for (int pt=0;pt<4;pt++){
        int p = pt*16 + l15;
        float v = acc[mt][pt][r]*et + b2f(yb[rowb + p]) + Dv * b2f(dtxb[dxb_ + p]) * di;
        S3[t*72 + p] = f2b(v);
      }
    }
  }
  for (int i=0;i<8;i++){
    int t = i*8 + tr; int g = ch*64 + t;
    int tph = d ? (LSEQ-1-g) : g;
    *(uint4*)(yb + ((size_t)b*LSEQ + tph)*DINNER + (size_t)h*64 + cb8) = *(uint4*)&S3[t*72 + cb8];
  }
}

// ---------------- gate: g=y*silu(z), per-dir rmsnorm, sum, ->bf16 ----------------
__global__ __launch_bounds__(256) void gate_k(const unsigned short* __restrict__ y0,
    const unsigned short* __restrict__ y1, const unsigned short* __restrict__ zcomp,
    const float* __restrict__ mnw, unsigned short* __restrict__ gsum){
  int tok = blockIdx.x; int tid = threadIdx.x;
  __shared__ float g0s[DINNER], g1s[DINNER];
  float ss0 = 0.f, ss1 = 0.f;
  for (int i=0;i<4;i++){
    int c = tid + i*256;
    float z = b2f(zcomp[(size_t)tok*DINNER + c]);
    float sz = z / (1.f + expf(-z));
    float g0 = b2f(y0[(size_t)tok*DINNER + c]) * sz;
    float g1 = b2f(y1[(size_t)tok*DINNER + c]) * sz;
    g0s[c] = g0; g1s[c] = g1;
    ss0 += g0*g0; ss1 += g1*g1;
  }
  for (int m=32;m>=1;m>>=1){ ss0 += __shfl_xor(ss0,m); ss1 += __shfl_xor(ss1,m); }
  __shared__ float w0[4], w1[4];
  int wave = tid>>6, lane = tid&63;
  if (lane==0){ w0[wave]=ss0; w1[wave]=ss1; }
  __syncthreads();
  ss0 = w0[0]+w0[1]+w0[2]+w0[3];
  ss1 = w1[0]+w1[1]+w1[2]+w1[3];
  float r0 = rsqrtf(ss0*(1.f/DINNER) + 1e-5f);
  float r1 = rsqrtf(ss1*(1.f/DINNER) + 1e-5f);
  for (int i=0;i<4;i++){
    int c = tid + i*256;
    gsum[(size_t)tok*DINNER + c] = f2b((g0s[c]*r0 + g1s[c]*r1) * mnw[c]);
  }
}

extern "C" void kernel_launch(void* const* d_in, const int* in_sizes, int n_in,
                              void* d_out, int out_size, void* d_ws, size_t ws_size,
                              hipStream_t stream){
  const float* x       = (const float*)d_in[0];
  const float* nin_w   = (const float*)d_in[1];
  const float* nin_b   = (const float*)d_in[2];
  const float* nout_w  = (const float*)d_in[3];
  const float* nout_b  = (const float*)d_in[4];
  const float* in_w    = (const float*)d_in[5];
  const float* conv_w  = (const float*)d_in[6];
  const float* conv_b  = (const float*)d_in[7];
  const float* dt_bias = (const float*)d_in[8];
  const float* A_log   = (const float*)d_in[9];
  const float* D_h     = (const float*)d_in[10];
  const float* mnorm_w = (const float*)d_in[11];
  const float* out_w   = (const float*)d_in[12];
  const float* ff_w1   = (const float*)d_in[13];
  const float* ff_b1   = (const float*)d_in[14];
  const float* ff_w2   = (const float*)d_in[15];
  const float* ff_b2   = (const float*)d_in[16];
  float* out = (float*)d_out;

  char* ws = (char*)d_ws;
  size_t off = 0;
  auto alloc = [&](size_t bytes)->char*{
    char* p = ws + off; off = (off + bytes + 255) & ~(size_t)255; return p; };
  unsigned short* xn_bf = (unsigned short*)alloc((size_t)NTOK*DMODEL*2);
  unsigned short* in_wT = (unsigned short*)alloc((size_t)NPAD*DMODEL*2);
  unsigned short* out_wT= (unsigned short*)alloc((size_t)DMODEL*DINNER*2);
  unsigned short* w1T   = (unsigned short*)alloc((size_t)2048*DMODEL*2);
  unsigned short* w2T   = (unsigned short*)alloc((size_t)DMODEL*2048*2);
  unsigned short* zx    = (unsigned short*)alloc((size_t)NTOK*NPAD*2);      // 37.7 MB
  unsigned short* zcomp = (unsigned short*)alloc((size_t)NTOK*DINNER*2);    // 16.8 MB
  float*          dAb   = (float*)alloc((size_t)2*NTOK*NHEADS*4);
  float*          dtb   = (float*)alloc((size_t)2*NTOK*NHEADS*4);
  unsigned short* Bb    = (unsigned short*)alloc((size_t)2*NTOK*DSTATE*2);
  unsigned short* Cb    = (unsigned short*)alloc((size_t)2*NTOK*DSTATE*2);
  unsigned short* dtxb  = (unsigned short*)alloc((size_t)2*NTOK*DINNER*2);  // 33.6 MB
  unsigned short* y0    = (unsigned short*)alloc((size_t)NTOK*DINNER*2);    // 16.8 MB
  unsigned short* y1    = (unsigned short*)alloc((size_t)NTOK*DINNER*2);    // 16.8 MB
  float*          Pch   = (float*)alloc((size_t)64*NCH*4);
  float*          ebuf  = (float*)alloc((size_t)64*NCH*64*4);               // 1.05 MB
  size_t need = off;
  if (need > ws_size) return;  // fail absmax cleanly instead of faulting

  // aliases into sequentially-dead regions:
  unsigned short* hbuf  = zx;                          // chunk states; zx dead after conv kernels
  unsigned short* gsum  = dtxb;                        // dtxb dead after ssd2_k
  float* mpre = (float*)(dtxb + (size_t)NTOK*DINNER);  // 2nd half of dtxb
  unsigned short* m_bf  = y0;                          // y0 dead after gate_k
  unsigned short* h1    = zx;                          // hbuf dead after ssd2_k

  // weight transposes -> bf16 [N][K]
  wconv_t<<<dim3(NPAD/32,   DMODEL/32), 256, 0, stream>>>(in_w,  in_wT,  DMODEL, DPROJ,  NPAD);
  wconv_t<<<dim3(DMODEL/32, DINNER/32), 256, 0, stream>>>(out_w, out_wT, DINNER, DMODEL, DMODEL);
  wconv_t<<<dim3(2048/32,   DMODEL/32), 256, 0, stream>>>(ff_w1, w1T,    DMODEL, 2048,   2048);
  wconv_t<<<dim3(DMODEL/32, 2048/32),   256, 0, stream>>>(ff_w2, w2T,    2048,   DMODEL, DMODEL);
  // LN in -> bf16
  layernorm_k<<<NTOK, 256, 0, stream>>>(x, nin_w, nin_b, xn_bf);
  // in_proj (shared between directions) -> bf16 zx
  gemm_k<<<dim3(NPAD/128, NTOK/128), 256, 0, stream>>>(xn_bf, in_wT, zx, NTOK, NPAD, DMODEL, 3, nullptr, nullptr);
  // dt/dA then conv (both directions from one pass) + z compaction
  dt_k<<<dim3(LSEQ/16, BSZ), 256, 0, stream>>>(zx, dt_bias, A_log, dAb, dtb);
  conv_x_k<<<dim3(LSEQ/32, BSZ), 256, 0, stream>>>(zx, conv_w, conv_b, dtb, dtxb, zcomp);
  conv_bc_k<<<dim3(LSEQ/64, BSZ), 256, 0, stream>>>(zx, conv_w, conv_b, Bb, Cb);
  // chunked SSD: intra-chunk (MFMA) -> combine -> inter-chunk (MFMA)
  ssd1_k<<<dim3(NCH, NHEADS, 2*BSZ), 64, 0, stream>>>(dAb, dtxb, Bb, Cb, y0, y1, hbuf, Pch, ebuf);
  comb_k<<<64, 256, 0, stream>>>(hbuf, Pch);
  ssd2_k<<<dim3(NCH, NHEADS, 2*BSZ), 64, 0, stream>>>(Cb, hbuf, dtxb, dtb, ebuf, D_h, y0, y1);
  // gate + per-dir rmsnorm + sum (linearity: single out_proj GEMM)
  gate_k<<<NTOK, 256, 0, stream>>>(y0, y1, zcomp, mnorm_w, gsum);
  // out_proj -> f32 mpre
  gemm_k<<<dim3(DMODEL/128, NTOK/128), 256, 0, stream>>>(gsum, out_wT, mpre, NTOK, DMODEL, DINNER, 0, nullptr, nullptr);
  // LN out -> bf16
  layernorm_k<<<NTOK, 256, 0, stream>>>(mpre, nout_w, nout_b, m_bf);
  // ff1 + gelu -> bf16
  gemm_k<<<dim3(2048/128, NTOK/128), 256, 0, stream>>>(m_bf, w1T, h1, NTOK, 2048, DMODEL, 1, ff_b1, nullptr);
  // ff2 + bias + residual -> f32 out
  gemm_k<<<dim3(DMODEL/128, NTOK/128), 256, 0, stream>>>(h1, w2T, out, NTOK, DMODEL, 2048, 2, ff_b2, x);
}

// Round 8
// 457.891 us; speedup vs baseline: 4.0594x; 1.0078x over previous
//
#include <hip/hip_runtime.h>
#include <hip/hip_bf16.h>

#define LSEQ 4096
#define BSZ 2
#define DMODEL 512
#define DINNER 1024
#define DSTATE 64
#define NHEADS 16
#define CONVDIM 1152
#define DPROJ 2192
#define NPAD 2304
#define NTOK (BSZ*LSEQ)
#define NCH 64   /* 64-token chunks */

typedef __attribute__((ext_vector_type(8))) short short8;
typedef __attribute__((ext_vector_type(4))) float f32x4;

__device__ inline unsigned short f2b(float v){
  unsigned int u = __builtin_bit_cast(unsigned int, v);
  unsigned int r = (u + 0x7FFFu + ((u >> 16) & 1u)) >> 16;
  return (unsigned short)r;
}
__device__ inline float b2f(unsigned short u){
  unsigned int x = ((unsigned int)u) << 16;
  return __builtin_bit_cast(float, x);
}
__device__ inline uint4 pack8(const float* v){
  uint4 pk;
  pk.x = (unsigned)f2b(v[0]) | ((unsigned)f2b(v[1])<<16);
  pk.y = (unsigned)f2b(v[2]) | ((unsigned)f2b(v[3])<<16);
  pk.z = (unsigned)f2b(v[4]) | ((unsigned)f2b(v[5])<<16);
  pk.w = (unsigned)f2b(v[6]) | ((unsigned)f2b(v[7])<<16);
  return pk;
}

#define GLL16(gp, lp) __builtin_amdgcn_global_load_lds( \
    (const __attribute__((address_space(1))) unsigned int*)(gp), \
    (__attribute__((address_space(3))) unsigned int*)(lp), 16, 0, 0)

// ---------------- weight transpose + f32->bf16 (src [K][Nsrc] -> dst [Npad][K]) ----
__global__ __launch_bounds__(256) void wconv_t(const float* __restrict__ src,
    unsigned short* __restrict__ dst, int K, int Nsrc, int Npad){
  __shared__ float t[32][33];
  int n0 = blockIdx.x*32, k0 = blockIdx.y*32;
  int tx = threadIdx.x & 31, ty = threadIdx.x >> 5;
  for (int i=0;i<4;i++){
    int k = k0 + ty + i*8; int n = n0 + tx;
    t[ty + i*8][tx] = (n < Nsrc) ? src[(size_t)k*Nsrc + n] : 0.f;
  }
  __syncthreads();
  for (int i=0;i<4;i++){
    int n = n0 + ty + i*8; int k = k0 + tx;
    if (n < Npad) dst[(size_t)n*K + k] = f2b(t[tx][ty + i*8]);
  }
}

// ---------------- layernorm over 512 cols (f32 in) -> bf16 ----------------
__global__ __launch_bounds__(256) void layernorm_k(const float* __restrict__ in,
    const float* __restrict__ w, const float* __restrict__ bb, unsigned short* __restrict__ out){
  int row = blockIdx.x; int tid = threadIdx.x;
  const float* r = in + (size_t)row*DMODEL;
  float v0 = r[tid], v1 = r[tid+256];
  float s = v0+v1, sq = v0*v0+v1*v1;
  for (int m=32;m>=1;m>>=1){ s += __shfl_xor(s,m); sq += __shfl_xor(sq,m); }
  __shared__ float ws_[4], wq_[4];
  int wave = tid>>6, lane = tid&63;
  if (lane==0){ ws_[wave]=s; wq_[wave]=sq; }
  __syncthreads();
  s = ws_[0]+ws_[1]+ws_[2]+ws_[3]; sq = wq_[0]+wq_[1]+wq_[2]+wq_[3];
  float mu = s * (1.f/DMODEL);
  float var = sq * (1.f/DMODEL) - mu*mu;
  float rs = rsqrtf(var + 1e-5f);
  out[(size_t)row*DMODEL + tid]     = f2b((v0-mu)*rs*w[tid] + bb[tid]);
  out[(size_t)row*DMODEL + tid+256] = f2b((v1-mu)*rs*w[tid+256] + bb[tid+256]);
}

// ---------------- bf16 MFMA GEMM: C[M,N] = A[M,K] @ Bt[N,K]^T ----------------
// Staging via global_load_lds width=16 (async direct-to-LDS, unpadded [128][32]).
// epi 0: f32 plain ; 1: bf16 gelu(v+bias) ; 2: f32 v+bias+resid ; 3: bf16 plain
__global__ __launch_bounds__(256) void gemm_k(const unsigned short* __restrict__ A,
    const unsigned short* __restrict__ Bt, void* __restrict__ outp,
    int M, int N, int K, int epi, const float* __restrict__ bias, const float* __restrict__ resid){
  __shared__ __align__(16) unsigned short smem[8320];   // 16640 B: staging 16384, epilogue 16640
  unsigned short* As = smem;                // [128][32]
  unsigned short* Bs = smem + 128*32;       // [128][32]
  int tid = threadIdx.x;
  int lane = tid & 63, wave = tid >> 6;
  int wr = wave >> 1, wc = wave & 1;
  int l15 = lane & 15, q = lane >> 4;
  int bm = blockIdx.y, bn = blockIdx.x;
  f32x4 acc[4][4];
  for (int i=0;i<4;i++) for(int j=0;j<4;j++) acc[i][j] = (f32x4){0.f,0.f,0.f,0.f};
  const size_t abase = (size_t)bm*128*K;
  const size_t bbase = (size_t)bn*128*K;
  for (int k0 = 0; k0 < K; k0 += 32){
    #pragma unroll
    for (int i=0;i<2;i++){
      int idx = tid + i*256; int rr = idx>>2, cg = idx&3;
      GLL16(A  + abase + (size_t)rr*K + k0 + cg*8, As + idx*8);
      GLL16(Bt + bbase + (size_t)rr*K + k0 + cg*8, Bs + idx*8);
    }
    __syncthreads();
    short8 af[4], bfr[4];
    for (int mt=0;mt<4;mt++) af[mt]  = *(const short8*)(&As[(wr*64+mt*16+l15)*32 + q*8]);
    for (int nt=0;nt<4;nt++) bfr[nt] = *(const short8*)(&Bs[(wc*64+nt*16+l15)*32 + q*8]);
    for (int mt=0;mt<4;mt++)
      for (int nt=0;nt<4;nt++)
        acc[mt][nt] = __builtin_amdgcn_mfma_f32_16x16x32_bf16(af[mt], bfr[nt], acc[mt][nt], 0,0,0);
    __syncthreads();
  }
  // ---- coalesced epilogue (per-wave 16x65-f32 LDS slab overlaying As/Bs) ----
  float* cbuf = ((float*)smem) + wave*1040;
  int rbase = q*4;
  int gr0t = bm*128 + wr*64;
  int gc0 = bn*128 + wc*64;
  for (int mt=0; mt<4; mt++){
    for (int nt=0;nt<4;nt++)
      for (int rr=0;rr<4;rr++)
        cbuf[(rbase+rr)*65 + nt*16 + l15] = acc[mt][nt][rr];
    int gr0 = gr0t + mt*16;
    if (epi == 1 || epi == 3){
      int r8 = lane >> 3, c0 = (lane & 7)*8;
      #pragma unroll
      for (int h=0; h<2; h++){
        int row = h*8 + r8;
        float v[8];
        #pragma unroll
        for (int t=0;t<8;t++) v[t] = cbuf[row*65 + c0 + t];
        if (epi == 1){
          #pragma unroll
          for (int t=0;t<8;t++){
            float bv = v[t] + bias[gc0 + c0 + t];
            v[t] = 0.5f*bv*(1.f+erff(bv*0.70710678118654752f));
          }
        }
        *(uint4*)((unsigned short*)outp + (size_t)(gr0+row)*N + gc0 + c0) = pack8(v);
      }
    } else {
      int r4 = lane >> 4, c0 = (lane & 15)*4;
      #pragma unroll
      for (int h=0; h<4; h++){
        int row = h*4 + r4;
        float4 v;
        v.x = cbuf[row*65 + c0 + 0];
        v.y = cbuf[row*65 + c0 + 1];
        v.z = cbuf[row*65 + c0 + 2];
        v.w = cbuf[row*65 + c0 + 3];
        if (epi == 2){
          const float4 rv = *(const float4*)(resid + (size_t)(gr0+row)*N + gc0 + c0);
          v.x += bias[gc0+c0+0] + rv.x;
          v.y += bias[gc0+c0+1] + rv.y;
          v.z += bias[gc0+c0+2] + rv.z;
          v.w += bias[gc0+c0+3] + rv.w;
        }
        *(float4*)((float*)outp + (size_t)(gr0+row)*N + gc0 + c0) = v;
      }
    }
  }
}

// ---------------- dt/dA per (token, head), written for both directions ----------------
__global__ __launch_bounds__(256) void dt_k(const unsigned short* __restrict__ zx,
    const float* __restrict__ dt_bias, const float* __restrict__ A_log,
    float* __restrict__ dAb, float* __restrict__ dtb){
  int b = blockIdx.y;
  int t = blockIdx.x*16 + (threadIdx.x>>4);
  int h = threadIdx.x & 15;
  float raw = b2f(zx[((size_t)b*LSEQ + t)*NPAD + (DINNER+CONVDIM) + h]) + dt_bias[h];
  float dt = (raw > 20.f) ? raw : log1pf(expf(raw));
  float dA = expf(-expf(A_log[h]) * dt);
  size_t f = ((size_t)b*LSEQ + t)*NHEADS + h;
  size_t r = ((size_t)(BSZ+b)*LSEQ + (LSEQ-1-t))*NHEADS + h;
  dAb[f] = dA; dtb[f] = dt;
  dAb[r] = dA; dtb[r] = dt;
}

// ---------------- conv+silu for x-channels, BOTH directions, + z compaction ----------
__global__ __launch_bounds__(256) void conv_x_k(const unsigned short* __restrict__ zx,
    const float* __restrict__ conv_w, const float* __restrict__ conv_b,
    const float* __restrict__ dtb, unsigned short* __restrict__ dtxb,
    unsigned short* __restrict__ zcomp){
  int b = blockIdx.y;
  int t0blk = blockIdx.x * 32;
  int tid = threadIdx.x;
  int half = tid >> 7, cg = tid & 127;
  int c0 = cg * 8;
  int head = c0 >> 6;
  float wk[4][8], bias8[8];
  #pragma unroll
  for (int k=0;k<4;k++)
    #pragma unroll
    for (int j=0;j<8;j++) wk[k][j] = conv_w[k*CONVDIM + c0 + j];
  #pragma unroll
  for (int j=0;j<8;j++) bias8[j] = conv_b[c0 + j];
  __shared__ float sdtf[32][16], sdtb[32][16];
  for (int r = tid; r < 512; r += 256){
    int i = r >> 4, h = r & 15;
    sdtf[i][h] = dtb[((size_t)b*LSEQ + t0blk + i)*NHEADS + h];
    sdtb[i][h] = dtb[((size_t)(BSZ+b)*LSEQ + (LSEQ-1-(t0blk+i)))*NHEADS + h];
  }
  __syncthreads();
  int t0 = t0blk + half*16;
  float w0[8],w1[8],w2[8],w3[8];
  #pragma unroll
  for (int j=0;j<8;j++){ w1[j]=0.f; w2[j]=0.f; w3[j]=0.f; }
  for (int it=0; it<22; ++it){
    int t = t0 - 3 + it;
    #pragma unroll
    for (int j=0;j<8;j++){ w0[j]=w1[j]; w1[j]=w2[j]; w2[j]=w3[j]; }
    if (t >= 0 && t < LSEQ){
      uint4 xv = *(const uint4*)(zx + ((size_t)b*LSEQ + t)*NPAD + DINNER + c0);
      const unsigned short* xs = (const unsigned short*)&xv;
      #pragma unroll
      for (int j=0;j<8;j++) w3[j] = b2f(xs[j]);
      if (t >= t0 && t < t0+16){
        uint4 zv = *(const uint4*)(zx + ((size_t)b*LSEQ + t)*NPAD + c0);
        *(uint4*)(zcomp + ((size_t)b*LSEQ + t)*DINNER + c0) = zv;
      }
    } else {
      #pragma unroll
      for (int j=0;j<8;j++) w3[j] = 0.f;
    }
    if (t >= t0 && t < t0+16){
      float dtf = sdtf[t - t0blk][head];
      float v[8];
      #pragma unroll
      for (int j=0;j<8;j++){
        float a = bias8[j] + wk[0][j]*w0[j] + wk[1][j]*w1[j] + wk[2][j]*w2[j] + wk[3][j]*w3[j];
        v[j] = (a / (1.f + expf(-a))) * dtf;
      }
      *(uint4*)(dtxb + ((size_t)b*LSEQ + t)*DINNER + c0) = pack8(v);
    }
    int tau = t - 3;
    if (tau >= t0 && tau < t0+16){
      float dtv = sdtb[tau - t0blk][head];
      float v[8];
      #pragma unroll
      for (int j=0;j<8;j++){
        float a = bias8[j] + wk[0][j]*w3[j] + wk[1][j]*w2[j] + wk[2][j]*w1[j] + wk[3][j]*w0[j];
        v[j] = (a / (1.f + expf(-a))) * dtv;
      }
      *(uint4*)(dtxb + ((size_t)(BSZ+b)*LSEQ + (LSEQ-1-tau))*DINNER + c0) = pack8(v);
    }
  }
}

// ---------------- conv+silu for B/C channels, both directions ----------------
__global__ __launch_bounds__(256) void conv_bc_k(const unsigned short* __restrict__ zx,
    const float* __restrict__ conv_w, const float* __restrict__ conv_b,
    unsigned short* __restrict__ Bb, unsigned short* __restrict__ Cb){
  int b = blockIdx.y;
  int t0blk = blockIdx.x * 64;
  int tid = threadIdx.x;
  int slot = tid >> 4, cg = tid & 15;
  int c0 = cg*8;
  int ccol = DINNER + 1024 + c0;
  int cw = 1024 + c0;
  float wk[4][8], bias8[8];
  #pragma unroll
  for (int k=0;k<4;k++)
    #pragma unroll
    for (int j=0;j<8;j++) wk[k][j] = conv_w[k*CONVDIM + cw + j];
  #pragma unroll
  for (int j=0;j<8;j++) bias8[j] = conv_b[cw + j];
  int t0 = t0blk + slot*4;
  float w0[8],w1[8],w2[8],w3[8];
  #pragma unroll
  for (int j=0;j<8;j++){ w1[j]=0.f; w2[j]=0.f; w3[j]=0.f; }
  for (int it=0; it<10; ++it){
    int t = t0 - 3 + it;
    #pragma unroll
    for (int j=0;j<8;j++){ w0[j]=w1[j]; w1[j]=w2[j]; w2[j]=w3[j]; }
    if (t >= 0 && t < LSEQ){
      uint4 xv = *(const uint4*)(zx + ((size_t)b*LSEQ + t)*NPAD + ccol);
      const unsigned short* xs = (const unsigned short*)&xv;
      #pragma unroll
      for (int j=0;j<8;j++) w3[j] = b2f(xs[j]);
    } else {
      #pragma unroll
      for (int j=0;j<8;j++) w3[j] = 0.f;
    }
    if (t >= t0 && t < t0+4){
      float v[8];
      #pragma unroll
      for (int j=0;j<8;j++){
        float a = bias8[j] + wk[0][j]*w0[j] + wk[1][j]*w1[j] + wk[2][j]*w2[j] + wk[3][j]*w3[j];
        v[j] = a / (1.f + expf(-a));
      }
      size_t tok = (size_t)b*LSEQ + t;
      if (c0 < 64) *(uint4*)(Bb + tok*DSTATE + c0)      = pack8(v);
      else         *(uint4*)(Cb + tok*DSTATE + (c0-64)) = pack8(v);
    }
    int tau = t - 3;
    if (tau >= t0 && tau < t0+4){
      float v[8];
      #pragma unroll
      for (int j=0;j<8;j++){
        float a = bias8[j] + wk[0][j]*w3[j] + wk[1][j]*w2[j] + wk[2][j]*w1[j] + wk[3][j]*w0[j];
        v[j] = a / (1.f + expf(-a));
      }
      size_t tok = (size_t)(BSZ+b)*LSEQ + (LSEQ-1-tau);
      if (c0 < 64) *(uint4*)(Bb + tok*DSTATE + c0)      = pack8(v);
      else         *(uint4*)(Cb + tok*DSTATE + (c0-64)) = pack8(v);
    }
  }
}

// ---- 64x64x64 bf16 GEMM on one wave: D += A(S-rows m, k contiguous) * B(S-rows n)^T
__device__ inline void gemm64(const unsigned short* Ab, const unsigned short* Bb_,
                              int l15, int q, f32x4 acc[4][4]){
  #pragma unroll
  for (int ks=0; ks<2; ks++){
    short8 af[4], bf4[4];
    #pragma unroll
    for (int mt=0;mt<4;mt++) af[mt]  = *(const short8*)(Ab  + (mt*16+l15)*72 + ks*32 + q*8);
    #pragma unroll
    for (int nt=0;nt<4;nt++) bf4[nt] = *(const short8*)(Bb_ + (nt*16+l15)*72 + ks*32 + q*8);
    #pragma unroll
    for (int mt=0;mt<4;mt++)
      #pragma unroll
      for (int nt=0;nt<4;nt++)
        acc[mt][nt] = __builtin_amdgcn_mfma_f32_16x16x32_bf16(af[mt], bf4[nt], acc[mt][nt], 0,0,0);
  }
}

// ---------------- SSD pass 1: per chunk: Y_intra (masked attention form) + local state G ----
__global__ __launch_bounds__(64) void ssd1_k(const float* __restrict__ dAb,
    const unsigned short* __restrict__ dtxb, const unsigned short* __restrict__ Bb,
    const unsigned short* __restrict__ Cb,
    unsigned short* __restrict__ y0, unsigned short* __restrict__ y1,
    unsigned short* __restrict__ hbuf, float* __restrict__ Pch, float* __restrict__ ebuf){
  int ch = blockIdx.x, h = blockIdx.y, z = blockIdx.z;
  int d = z >> 1, b = z & 1;
  int lane = threadIdx.x;
  int l15 = lane & 15, q = lane >> 4;
  int tr = lane >> 3, cb8 = (lane & 7)*8;
  size_t tokb = (size_t)z*LSEQ + (size_t)ch*64;
  size_t zhc = ((size_t)z*NHEADS + h)*NCH + ch;
  __shared__ __align__(16) unsigned short S1[64*72];
  __shared__ __align__(16) unsigned short S2[64*72];
  __shared__ __align__(16) unsigned short S3[64*72];
  __shared__ float Lb[64];
  float L = fmaxf(logf(dAb[(tokb + lane)*NHEADS + h]), -60.f);
  #pragma unroll
  for (int off=1; off<64; off<<=1){
    float v = __shfl_up(L, off);
    if (lane >= off) L += v;
  }
  Lb[lane] = L;
  float e = expf(L);
  ebuf[zhc*64 + lane] = e;
  if (lane == 63) Pch[zhc] = e;
  for (int i=0;i<8;i++){
    int t = i*8 + tr;
    *(uint4*)&S1[t*72 + cb8] = *(const uint4*)(Cb + (tokb+t)*DSTATE + cb8);
    *(uint4*)&S2[t*72 + cb8] = *(const uint4*)(Bb + (tokb+t)*DSTATE + cb8);
    uint4 xv = *(const uint4*)(dtxb + (tokb+t)*DINNER + (size_t)h*64 + cb8);
    const unsigned short* xs = (const unsigned short*)&xv;
    #pragma unroll
    for (int j=0;j<8;j++) S3[(cb8+j)*72 + t] = xs[j];
  }
  f32x4 sa[4][4];
  for (int i=0;i<4;i++) for (int j=0;j<4;j++) sa[i][j] = (f32x4){0.f,0.f,0.f,0.f};
  gemm64(S1, S2, l15, q, sa);
  float Lsv[4];
  #pragma unroll
  for (int nt=0;nt<4;nt++) Lsv[nt] = Lb[nt*16 + l15];
  #pragma unroll
  for (int mt=0;mt<4;mt++){
    #pragma unroll
    for (int r=0;r<4;r++){
      int t = mt*16 + q*4 + r;
      float Lt = Lb[t];
      #pragma unroll
      for (int nt=0;nt<4;nt++){
        int s = nt*16 + l15;
        float v = (t >= s) ? expf(Lt - Lsv[nt]) * sa[mt][nt][r] : 0.f;
        S1[t*72 + s] = f2b(v);
      }
    }
  }
  f32x4 ya[4][4];
  for (int i=0;i<4;i++) for (int j=0;j<4;j++) ya[i][j] = (f32x4){0.f,0.f,0.f,0.f};
  gemm64(S1, S3, l15, q, ya);
  #pragma unroll
  for (int mt=0;mt<4;mt++)
    #pragma unroll
    for (int pt=0;pt<4;pt++)
      #pragma unroll
      for (int r=0;r<4;r++)
        S2[(mt*16+q*4+r)*72 + pt*16 + l15] = f2b(ya[mt][pt][r]);
  unsigned short* yb = d ? y1 : y0;
  for (int i=0;i<8;i++){
    int t = i*8 + tr; int g = ch*64 + t;
    int tph = d ? (LSEQ-1-g) : g;
    *(uint4*)(yb + ((size_t)b*LSEQ + tph)*DINNER + (size_t)h*64 + cb8) = *(uint4*)&S2[t*72 + cb8];
  }
  float L63 = Lb[63];
  for (int i=0;i<8;i++){
    int s = i*8 + tr;
    float w = expf(L63 - Lb[s]);
    uint4 bv = *(const uint4*)(Bb + (tokb+s)*DSTATE + cb8);
    const unsigned short* bs = (const unsigned short*)&bv;
    #pragma unroll
    for (int j=0;j<8;j++) S2[(cb8+j)*72 + s] = f2b(w * b2f(bs[j]));
  }
  f32x4 ga[4][4];
  for (int i=0;i<4;i++) for (int j=0;j<4;j++) ga[i][j] = (f32x4){0.f,0.f,0.f,0.f};
  gemm64(S3, S2, l15, q, ga);
  #pragma unroll
  for (int pt=0;pt<4;pt++)
    #pragma unroll
    for (int nt=0;nt<4;nt++)
      #pragma unroll
      for (int r=0;r<4;r++)
        S1[(pt*16+q*4+r)*72 + nt*16 + l15] = f2b(ga[pt][nt][r]);
  for (int i=0;i<8;i++){
    int p = i*8 + tr;
    *(uint4*)(hbuf + zhc*4096 + (size_t)p*64 + cb8) = *(uint4*)&S1[p*72 + cb8];
  }
}

// ---------------- combine chunk states, IN PLACE ----------------
__global__ __launch_bounds__(256) void comb_k(unsigned short* __restrict__ hbuf,
    const float* __restrict__ Pch){
  int u = blockIdx.x; int tid = threadIdx.x;
  float hreg[16];
  #pragma unroll
  for (int k=0;k<16;k++) hreg[k]=0.f;
  for (int ch=0; ch<NCH; ch++){
    size_t base = ((size_t)u*NCH + ch)*4096;
    float P = Pch[(size_t)u*NCH + ch];
    #pragma unroll
    for (int k=0;k<16;k++){
      float t = b2f(hbuf[base + tid + k*256]);
      hbuf[base + tid + k*256] = f2b(hreg[k]);
      hreg[k] = hreg[k]*P + t;
    }
  }
}

// ---------------- SSD pass 2: Y += diag(e) C h_in^T + D*xh ----------------
__global__ __launch_bounds__(64) void ssd2_k(const unsigned short* __restrict__ Cb,
    const unsigned short* __restrict__ hbuf, const unsigned short* __restrict__ dtxb,
    const float* __restrict__ dtb, const float* __restrict__ ebuf, const float* __restrict__ Dh,
    unsigned short* __restrict__ y0, unsigned short* __restrict__ y1){
  int ch = blockIdx.x, h = blockIdx.y, z = blockIdx.z;
  int d = z >> 1, b = z & 1;
  int lane = threadIdx.x;
  int l15 = lane & 15, q = lane >> 4;
  int tr = lane >> 3, cb8 = (lane & 7)*8;
  size_t tokb = (size_t)z*LSEQ + (size_t)ch*64;
  size_t zhc = ((size_t)z*NHEADS + h)*NCH + ch;
  __shared__ __align__(16) unsigned short S1[64*72];
  __shared__ __align__(16) unsigned short S2[64*72];
  __shared__ __align__(16) unsigned short S3[64*72];
  __shared__ float eb2[64], dti[64];
  eb2[lane] = ebuf[zhc*64 + lane];
  dti[lane] = 1.f / dtb[(tokb + lane)*NHEADS + h];
  float Dv = Dh[h];
  for (int i=0;i<8;i++){
    int t = i*8 + tr;
    *(uint4*)&S1[t*72 + cb8] = *(const uint4*)(Cb + (tokb+t)*DSTATE + cb8);
    *(uint4*)&S2[t*72 + cb8] = *(const uint4*)(hbuf + zhc*4096 + (size_t)t*64 + cb8);
  }
  f32x4 acc[4][4];
  for (int i=0;i<4;i++) for (int j=0;j<4;j++) acc[i][j] = (f32x4){0.f,0.f,0.f,0.f};
  gemm64(S1, S2, l15, q, acc);
  unsigned short* yb = d ? y1 : y0;
  #pragma unroll
  for (int mt=0;mt<4;mt++){
    #pragma unroll
    for (int r=0;r<4;r++){
      int t = mt*16 + q*4 + r; int g = ch*64 + t;
      int tph = d ? (LSEQ-1-g) : g;
      size_t rowb = ((size_t)b*LSEQ + tph)*DINNER + (size_t)h*64;
      size_t dxb_ = (tokb + t)*DINNER + (size_t)h*64;
      float et = eb2[t], di = dti[t];
      #pragma unroll
      for (int pt=0;pt<4;pt++){
        int p = pt*16 + l15;
        float v = acc[mt][pt][r]*et + b2f(yb[rowb + p]) + Dv * b2f(dtxb[dxb_ + p]) * di;
        S3[t*72 + p] = f2b(v);
      }
    }
  }
  for (int i=0;i<8;i++){
    int t = i*8 + tr; int g = ch*64 + t;
    int tph = d ? (LSEQ-1-g) : g;
    *(uint4*)(yb + ((size_t)b*LSEQ + tph)*DINNER + (size_t)h*64 + cb8) = *(uint4*)&S3[t*72 + cb8];
  }
}

// ---------------- gate: g=y*silu(z), per-dir rmsnorm, sum, ->bf16 ----------------
__global__ __launch_bounds__(256) void gate_k(const unsigned short* __restrict__ y0,
    const unsigned short* __restrict__ y1, const unsigned short* __restrict__ zcomp,
    const float* __restrict__ mnw, unsigned short* __restrict__ gsum){
  int tok = blockIdx.x; int tid = threadIdx.x;
  __shared__ float g0s[DINNER], g1s[DINNER];
  float ss0 = 0.f, ss1 = 0.f;
  for (int i=0;i<4;i++){
    int c = tid + i*256;
    float z = b2f(zcomp[(size_t)tok*DINNER + c]);
    float sz = z / (1.f + expf(-z));
    float g0 = b2f(y0[(size_t)tok*DINNER + c]) * sz;
    float g1 = b2f(y1[(size_t)tok*DINNER + c]) * sz;
    g0s[c] = g0; g1s[c] = g1;
    ss0 += g0*g0; ss1 += g1*g1;
  }
  for (int m=32;m>=1;m>>=1){ ss0 += __shfl_xor(ss0,m); ss1 += __shfl_xor(ss1,m); }
  __shared__ float w0[4], w1[4];
  int wave = tid>>6, lane = tid&63;
  if (lane==0){ w0[wave]=ss0; w1[wave]=ss1; }
  __syncthreads();
  ss0 = w0[0]+w0[1]+w0[2]+w0[3];
  ss1 = w1[0]+w1[1]+w1[2]+w1[3];
  float r0 = rsqrtf(ss0*(1.f/DINNER) + 1e-5f);
  float r1 = rsqrtf(ss1*(1.f/DINNER) + 1e-5f);
  for (int i=0;i<4;i++){
    int c = tid + i*256;
    gsum[(size_t)tok*DINNER + c] = f2b((g0s[c]*r0 + g1s[c]*r1) * mnw[c]);
  }
}

extern "C" void kernel_launch(void* const* d_in, const int* in_sizes, int n_in,
                              void* d_out, int out_size, void* d_ws, size_t ws_size,
                              hipStream_t stream){
  const float* x       = (const float*)d_in[0];
  const float* nin_w   = (const float*)d_in[1];
  const float* nin_b   = (const float*)d_in[2];
  const float* nout_w  = (const float*)d_in[3];
  const float* nout_b  = (const float*)d_in[4];
  const float* in_w    = (const float*)d_in[5];
  const float* conv_w  = (const float*)d_in[6];
  const float* conv_b  = (const float*)d_in[7];
  const float* dt_bias = (const float*)d_in[8];
  const float* A_log   = (const float*)d_in[9];
  const float* D_h     = (const float*)d_in[10];
  const float* mnorm_w = (const float*)d_in[11];
  const float* out_w   = (const float*)d_in[12];
  const float* ff_w1   = (const float*)d_in[13];
  const float* ff_b1   = (const float*)d_in[14];
  const float* ff_w2   = (const float*)d_in[15];
  const float* ff_b2   = (const float*)d_in[16];
  float* out = (float*)d_out;

  char* ws = (char*)d_ws;
  size_t off = 0;
  auto alloc = [&](size_t bytes)->char*{
    char* p = ws + off; off = (off + bytes + 255) & ~(size_t)255; return p; };
  unsigned short* xn_bf = (unsigned short*)alloc((size_t)NTOK*DMODEL*2);
  unsigned short* in_wT = (unsigned short*)alloc((size_t)NPAD*DMODEL*2);
  unsigned short* out_wT= (unsigned short*)alloc((size_t)DMODEL*DINNER*2);
  unsigned short* w1T   = (unsigned short*)alloc((size_t)2048*DMODEL*2);
  unsigned short* w2T   = (unsigned short*)alloc((size_t)DMODEL*2048*2);
  unsigned short* zx    = (unsigned short*)alloc((size_t)NTOK*NPAD*2);      // 37.7 MB
  unsigned short* zcomp = (unsigned short*)alloc((size_t)NTOK*DINNER*2);    // 16.8 MB
  float*          dAb   = (float*)alloc((size_t)2*NTOK*NHEADS*4);
  float*          dtb   = (float*)alloc((size_t)2*NTOK*NHEADS*4);
  unsigned short* Bb    = (unsigned short*)alloc((size_t)2*NTOK*DSTATE*2);
  unsigned short* Cb    = (unsigned short*)alloc((size_t)2*NTOK*DSTATE*2);
  unsigned short* dtxb  = (unsigned short*)alloc((size_t)2*NTOK*DINNER*2);  // 33.6 MB
  unsigned short* y0    = (unsigned short*)alloc((size_t)NTOK*DINNER*2);    // 16.8 MB
  unsigned short* y1    = (unsigned short*)alloc((size_t)NTOK*DINNER*2);    // 16.8 MB
  float*          Pch   = (float*)alloc((size_t)64*NCH*4);
  float*          ebuf  = (float*)alloc((size_t)64*NCH*64*4);               // 1.05 MB
  size_t need = off;
  if (need > ws_size) return;  // fail absmax cleanly instead of faulting

  // aliases into sequentially-dead regions:
  unsigned short* hbuf  = zx;                          // chunk states; zx dead after conv kernels
  unsigned short* gsum  = dtxb;                        // dtxb dead after ssd2_k
  float* mpre = (float*)(dtxb + (size_t)NTOK*DINNER);  // 2nd half of dtxb
  unsigned short* m_bf  = y0;                          // y0 dead after gate_k
  unsigned short* h1    = zx;                          // hbuf dead after ssd2_k

  // weight transposes -> bf16 [N][K]
  wconv_t<<<dim3(NPAD/32,   DMODEL/32), 256, 0, stream>>>(in_w,  in_wT,  DMODEL, DPROJ,  NPAD);
  wconv_t<<<dim3(DMODEL/32, DINNER/32), 256, 0, stream>>>(out_w, out_wT, DINNER, DMODEL, DMODEL);
  wconv_t<<<dim3(2048/32,   DMODEL/32), 256, 0, stream>>>(ff_w1, w1T,    DMODEL, 2048,   2048);
  wconv_t<<<dim3(DMODEL/32, 2048/32),   256, 0, stream>>>(ff_w2, w2T,    2048,   DMODEL, DMODEL);
  // LN in -> bf16
  layernorm_k<<<NTOK, 256, 0, stream>>>(x, nin_w, nin_b, xn_bf);
  // in_proj (shared between directions) -> bf16 zx
  gemm_k<<<dim3(NPAD/128, NTOK/128), 256, 0, stream>>>(xn_bf, in_wT, zx, NTOK, NPAD, DMODEL, 3, nullptr, nullptr);
  // dt/dA then conv (both directions from one pass) + z compaction
  dt_k<<<dim3(LSEQ/16, BSZ), 256, 0, stream>>>(zx, dt_bias, A_log, dAb, dtb);
  conv_x_k<<<dim3(LSEQ/32, BSZ), 256, 0, stream>>>(zx, conv_w, conv_b, dtb, dtxb, zcomp);
  conv_bc_k<<<dim3(LSEQ/64, BSZ), 256, 0, stream>>>(zx, conv_w, conv_b, Bb, Cb);
  // chunked SSD: intra-chunk (MFMA) -> combine -> inter-chunk (MFMA)
  ssd1_k<<<dim3(NCH, NHEADS, 2*BSZ), 64, 0, stream>>>(dAb, dtxb, Bb, Cb, y0, y1, hbuf, Pch, ebuf);
  comb_k<<<64, 256, 0, stream>>>(hbuf, Pch);
  ssd2_k<<<dim3(NCH, NHEADS, 2*BSZ), 64, 0, stream>>>(Cb, hbuf, dtxb, dtb, ebuf, D_h, y0, y1);
  // gate + per-dir rmsnorm + sum (linearity: single out_proj GEMM)
  gate_k<<<NTOK, 256, 0, stream>>>(y0, y1, zcomp, mnorm_w, gsum);
  // out_proj -> f32 mpre
  gemm_k<<<dim3(DMODEL/128, NTOK/128), 256, 0, stream>>>(gsum, out_wT, mpre, NTOK, DMODEL, DINNER, 0, nullptr, nullptr);
  // LN out -> bf16
  layernorm_k<<<NTOK, 256, 0, stream>>>(mpre, nout_w, nout_b, m_bf);
  // ff1 + gelu -> bf16
  gemm_k<<<dim3(2048/128, NTOK/128), 256, 0, stream>>>(m_bf, w1T, h1, NTOK, 2048, DMODEL, 1, ff_b1, nullptr);
  // ff2 + bias + residual -> f32 out
  gemm_k<<<dim3(DMODEL/128, NTOK/128), 256, 0, stream>>>(h1, w2T, out, NTOK, DMODEL, 2048, 2, ff_b2, x);
}